// Round 5
// baseline (581.710 us; speedup 1.0000x reference)
//
#include <hip/hip_runtime.h>
#include <hip/hip_bf16.h>
#include <stdint.h>

#define QLEN 1024
#define MLEN 1024
#define KLEN 2048
#define BSZ 4
#define NH 16
#define DH 64
#define DM 1024

typedef __attribute__((ext_vector_type(8))) short bf16x8;
typedef __attribute__((ext_vector_type(4))) float f32x4;
typedef unsigned short u16;
typedef unsigned int u32;

typedef unsigned int __attribute__((address_space(1))) gu32;
typedef unsigned int __attribute__((address_space(3))) lu32;

__device__ __forceinline__ void stage16(const void* g, void* l){
  __builtin_amdgcn_global_load_lds((const gu32*)g, (lu32*)l, 16, 0, 0);
}

__device__ __forceinline__ u16 f2b(float f){
  u32 u = __builtin_bit_cast(u32, f);
  u32 r = (u + 0x7FFFu + ((u >> 16) & 1u)) >> 16;
  return (u16)r;
}
__device__ __forceinline__ float b2f(u16 v){
  u32 u = ((u32)v) << 16;
  return __builtin_bit_cast(float, u);
}
// native converts (compiler emits v_cvt_pk_bf16_f32); bits via memcpy since
// __hip_bfloat16 types are not trivially copyable (no bit_cast).
__device__ __forceinline__ u16 f2bn(float f){
  __hip_bfloat16 h = __float2bfloat16(f);
  u16 r; __builtin_memcpy(&r, &h, 2); return r;
}
__device__ __forceinline__ u32 pk2(float a, float b){
  float2 t; t.x = a; t.y = b;
  __hip_bfloat162 h = __float22bfloat162_rn(t);
  u32 r; __builtin_memcpy(&r, &h, 4); return r;
}

// XOR swizzle for [rows][64]bf16 tiles (128B rows)
__device__ __forceinline__ int swz(int row, int byteoff){
  return (row << 7) + (byteoff ^ (((row ^ (row >> 3)) & 7) << 4));
}

// DPP 16-lane-row reductions (row_ror:N = 0x120+N)
template<int C>
__device__ __forceinline__ float dppmax(float x){
  int t = __builtin_amdgcn_update_dpp(0, __builtin_bit_cast(int, x), C, 0xf, 0xf, true);
  return fmaxf(x, __builtin_bit_cast(float, t));
}
template<int C>
__device__ __forceinline__ float dppadd(float x){
  int t = __builtin_amdgcn_update_dpp(0, __builtin_bit_cast(int, x), C, 0xf, 0xf, true);
  return x + __builtin_bit_cast(float, t);
}

#define MFMA16(a, b, c) __builtin_amdgcn_mfma_f32_16x16x32_bf16(a, b, c, 0, 0, 0)

// ---------------- conversion kernels ----------------

__global__ __launch_bounds__(256) void conv_cat(const float* __restrict__ mems,
                                                const float* __restrict__ w,
                                                u16* __restrict__ dst){
  int idx = blockIdx.x * 256 + threadIdx.x;
  const int memf4 = MLEN * BSZ * DM / 4;
  float4 v = (idx < memf4) ? ((const float4*)mems)[idx]
                           : ((const float4*)w)[idx - memf4];
  ushort4 o;
  o.x = f2b(v.x); o.y = f2b(v.y); o.z = f2b(v.z); o.w = f2b(v.w);
  ((ushort4*)dst)[idx] = o;
}

__global__ __launch_bounds__(256) void conv_r(const float* __restrict__ r,
                                              u16* __restrict__ dst){
  int idx = blockIdx.x * 256 + threadIdx.x;
  float4 v = ((const float4*)r)[idx];
  ushort4 o;
  o.x = f2b(v.x); o.y = f2b(v.y); o.z = f2b(v.z); o.w = f2b(v.w);
  ((ushort4*)dst)[idx] = o;
}

__global__ __launch_bounds__(256) void transpose_conv(const float* __restrict__ src,
                                                      u16* __restrict__ dst,
                                                      int R, int C){
  __shared__ float tile[32][33];
  int c0 = blockIdx.x * 32, r0 = blockIdx.y * 32;
  int tx = threadIdx.x & 31, ty = threadIdx.x >> 5;
  #pragma unroll
  for (int rr = ty; rr < 32; rr += 8)
    tile[rr][tx] = src[(size_t)(r0 + rr) * C + c0 + tx];
  __syncthreads();
  #pragma unroll
  for (int rr = ty; rr < 32; rr += 8)
    dst[(size_t)(c0 + rr) * R + r0 + tx] = f2b(tile[tx][rr]);
}

// ---------------- generic bf16 MFMA GEMM (128x128 tile, BK=32) ----------------
// MODE 0: QKV projection epilogue (q raw [bh][t][d]; k [bh][t][d]; v d-major [bh][d][t])
// MODE 1: R projection epilogue (rh in [h][t][d])
// MODE 3: plain f32 row-major C

template<int MODE>
__global__ __launch_bounds__(256, 2) void gemm_k(
    const u16* __restrict__ A, const u16* __restrict__ Bt, int K,
    void* __restrict__ o0, void* __restrict__ o1, void* __restrict__ o2)
{
  __shared__ u16 As[128 * 32];
  __shared__ u16 Bs[128 * 32];
  const int tid = threadIdx.x;
  const int lane = tid & 63, w = tid >> 6;
  const int wr = w >> 1, wc = w & 1;
  const int lr = lane >> 4, lc = lane & 15;
  const int m0 = blockIdx.y * 128, n0 = blockIdx.x * 128;

  f32x4 acc[4][4];
  #pragma unroll
  for (int i = 0; i < 4; i++)
    #pragma unroll
    for (int j = 0; j < 4; j++)
      acc[i][j] = (f32x4){0.f, 0.f, 0.f, 0.f};

  for (int k0 = 0; k0 < K; k0 += 32){
    #pragma unroll
    for (int rnd = 0; rnd < 2; rnd++){
      int c = rnd * 256 + w * 64 + lane;
      int row = c >> 2, kc = c & 3;
      stage16((const char*)A + ((size_t)(m0 + row) * K + k0 + kc * 8) * 2,
              (char*)As + (rnd * 256 + w * 64) * 16);
      stage16((const char*)Bt + ((size_t)(n0 + row) * K + k0 + kc * 8) * 2,
              (char*)Bs + (rnd * 256 + w * 64) * 16);
    }
    asm volatile("s_waitcnt vmcnt(0)");
    __syncthreads();

    bf16x8 af[4], bfr[4];
    #pragma unroll
    for (int mf = 0; mf < 4; mf++)
      af[mf] = *(const bf16x8*)((const char*)As + (wr * 64 + mf * 16 + lc) * 64 + lr * 16);
    #pragma unroll
    for (int nf = 0; nf < 4; nf++)
      bfr[nf] = *(const bf16x8*)((const char*)Bs + (wc * 64 + nf * 16 + lc) * 64 + lr * 16);
    #pragma unroll
    for (int mf = 0; mf < 4; mf++)
      #pragma unroll
      for (int nf = 0; nf < 4; nf++)
        acc[mf][nf] = MFMA16(af[mf], bfr[nf], acc[mf][nf]);
    __syncthreads();
  }

  #pragma unroll
  for (int mf = 0; mf < 4; mf++){
    #pragma unroll
    for (int nf = 0; nf < 4; nf++){
      #pragma unroll
      for (int e = 0; e < 4; e++){
        float v = acc[mf][nf][e];
        int row = m0 + wr * 64 + mf * 16 + lr * 4 + e;
        int col = n0 + wc * 64 + nf * 16 + lc;
        if constexpr (MODE == 0){
          int t = row >> 2, bb = row & 3;
          int s = col >> 10, rem = col & 1023;
          int h = rem >> 6, d = rem & 63;
          if (s == 0){
            if (t >= MLEN)
              ((u16*)o0)[((size_t)(bb * NH + h) * QLEN + (t - MLEN)) * DH + d] = f2b(v);
          } else if (s == 1){
            ((u16*)o1)[((size_t)(bb * NH + h) * KLEN + t) * DH + d] = f2b(v);    // k [bh][t][d]
          } else {
            ((u16*)o2)[((size_t)(bb * NH + h) * DH + d) * KLEN + t] = f2b(v);    // v [bh][d][t]
          }
        } else if constexpr (MODE == 1){
          int h = col >> 6, d = col & 63;
          ((u16*)o0)[((size_t)h * KLEN + row) * DH + d] = f2b(v);
        } else {
          ((float*)o0)[(size_t)row * DM + col] = v;
        }
      }
    }
  }
}

// ---------------- fused flash attention, 128-row blocks, 8 waves ----------------
// Per wave: 16 q-rows. BD band per wave starts at t0-16w so the sheared pickup
// index (jl - r) & 63 is wave-independent. K/V staged via global_load_lds
// (V stored d-major by the GEMM); rh B-fragments loaded per-lane from global
// (L2-resident). Counted vmcnt, raw barriers, exact defer-rescale.

__global__ __launch_bounds__(512, 4) void attn_k(
    const u16* __restrict__ qB,  const u16* __restrict__ kB,
    const u16* __restrict__ vB,  const u16* __restrict__ rhB,
    const float* __restrict__ rwb, const float* __restrict__ rrb,
    u16* __restrict__ av)
{
  __shared__ u16 Kt[2][64 * 64];      // [j][d] swizzled          16 KB
  __shared__ u16 Vt[2][64 * 64];      // [d][j] swizzled          16 KB
  __shared__ u16 Pt[8][16 * 64];      // per-wave P [row][j] swz  16 KB
  __shared__ u16 Pbd[8][2][64 * 16];  // per-wave BD [t'][r] oct-XOR, parity dbuf  32 KB

  const int tid = threadIdx.x, lane = tid & 63, w = tid >> 6;
  const int lr = lane >> 4, lc = lane & 15;

  // XCD remap + balanced i-block pairing (0,7),(1,6),(2,5),(3,4)
  const int bid = blockIdx.x;
  const int nid = (bid & 7) * 64 + (bid >> 3);
  const int tt = nid & 7;
  const int iblk = (tt & 1) ? (7 - (tt >> 1)) : (tt >> 1);
  const int i0 = iblk * 128;
  const int h  = (nid >> 3) & 15;
  const int b  = nid >> 7;
  const size_t bh = (size_t)b * NH + h;

  // staging constants: 512 threads cover one 64x64 bf16 tile (8 KB)
  const int srow = tid >> 3;
  const int sch  = (tid & 7) ^ ((srow ^ (srow >> 3)) & 7);

  // Q A-fragments with biases (rows i0 + w*16 + lc)
  bf16x8 qw_[2], qr_[2];
  #pragma unroll
  for (int ks = 0; ks < 2; ks++){
    bf16x8 qv = *(const bf16x8*)(qB + (bh * QLEN + i0 + w * 16 + lc) * DH + ks * 32 + lr * 8);
    #pragma unroll
    for (int e2 = 0; e2 < 8; e2++){
      int d = ks * 32 + lr * 8 + e2;
      float q32 = b2f((u16)qv[e2]);
      qw_[ks][e2] = (short)f2bn(q32 + rwb[h * DH + d]);
      qr_[ks][e2] = (short)f2bn(q32 + rrb[h * DH + d]);
    }
  }

  f32x4 O[4];
  float mx[4], sm[4];
  #pragma unroll
  for (int df = 0; df < 4; df++) O[df] = (f32x4){0.f, 0.f, 0.f, 0.f};
  #pragma unroll
  for (int e = 0; e < 4; e++){ mx[e] = -3.0e38f; sm[e] = 0.f; }

  const char* kgb = (const char*)(kB + bh * (size_t)KLEN * DH);
  const char* vgb = (const char*)(vB + bh * (size_t)KLEN * DH);   // [DH][KLEN]
  const char* rgb = (const char*)(rhB + (size_t)h * KLEN * DH);

  const int jtiles = (i0 >> 6) + 18;
  const int twbase = 1023 - i0 - 16 * w;   // per-wave band origin at j0=0

  bf16x8 rhf[2][4];

  // ---- prologue: prev band BD -> Pbd[w][1]; stage tile 0 ----
  {
    #pragma unroll
    for (int ks = 0; ks < 2; ks++)
      #pragma unroll
      for (int n2 = 0; n2 < 4; n2++){
        int t = twbase - 64 + n2 * 16 + lc; t = t < 0 ? 0 : t;
        rhf[ks][n2] = *(const bf16x8*)(rgb + (size_t)t * 128 + ks * 64 + lr * 16);
      }
    __builtin_amdgcn_sched_barrier(0);
    stage16(kgb + (size_t)srow * 128 + sch * 16, (char*)&Kt[0][0] + tid * 16);
    stage16(vgb + (size_t)srow * 4096 + sch * 16, (char*)&Vt[0][0] + tid * 16);
    __builtin_amdgcn_sched_barrier(0);
    asm volatile("s_waitcnt vmcnt(2)" ::: "memory");
    __builtin_amdgcn_sched_barrier(0);
    #pragma unroll
    for (int n2 = 0; n2 < 4; n2++){
      f32x4 z = (f32x4){0.f, 0.f, 0.f, 0.f};
      z = MFMA16(qr_[0], rhf[0][n2], z);
      z = MFMA16(qr_[1], rhf[1][n2], z);
      int tp = n2 * 16 + lc;
      uint2 pr; pr.x = pk2(z[0], z[1]); pr.y = pk2(z[2], z[3]);
      *(uint2*)((char*)&Pbd[w][1][0] + tp * 32 + ((lr * 8) ^ (((tp >> 2) & 3) << 3))) = pr;
    }
  }

  for (int jt = 0; jt < jtiles; jt++){
    const int j0 = jt * 64;
    const int cur = jt & 1, nxt = cur ^ 1;
    const int tw0 = twbase + j0;

    // 1. rh loads for current band (8 in flight)
    #pragma unroll
    for (int ks = 0; ks < 2; ks++)
      #pragma unroll
      for (int n2 = 0; n2 < 4; n2++){
        int t = tw0 + n2 * 16 + lc; t = t > 2047 ? 2047 : t;
        rhf[ks][n2] = *(const bf16x8*)(rgb + (size_t)t * 128 + ks * 64 + lr * 16);
      }
    __builtin_amdgcn_sched_barrier(0);
    // 2. stage next K/V tiles (into [nxt]); last iter restages current (harmless)
    {
      int jn = (jt + 1 < jtiles) ? j0 + 64 : j0;
      stage16(kgb + (size_t)(jn + srow) * 128 + sch * 16, (char*)&Kt[nxt][0] + tid * 16);
      stage16(vgb + (size_t)srow * 4096 + jn * 2 + sch * 16, (char*)&Vt[nxt][0] + tid * 16);
    }
    __builtin_amdgcn_sched_barrier(0);
    // 3+4. wait current-tile stages (8 rh + 2 nxt stages stay in flight), sync
    asm volatile("s_waitcnt vmcnt(10)" ::: "memory");
    __builtin_amdgcn_s_barrier();

    // 5. AC = (q + r_w_bias) K^T
    f32x4 s[4];
    __builtin_amdgcn_s_setprio(1);
    #pragma unroll
    for (int n = 0; n < 4; n++){
      bf16x8 k0f = *(const bf16x8*)((const char*)&Kt[cur][0] + swz(n * 16 + lc, lr * 16));
      bf16x8 k1f = *(const bf16x8*)((const char*)&Kt[cur][0] + swz(n * 16 + lc, 64 + lr * 16));
      f32x4 z = (f32x4){0.f, 0.f, 0.f, 0.f};
      z = MFMA16(qw_[0], k0f, z);
      z = MFMA16(qw_[1], k1f, z);
      s[n] = z;
    }
    // 6+7. BD band -> Pbd[w][cur] (b64 writes via cvt_pk)
    asm volatile("s_waitcnt vmcnt(2)" ::: "memory");
    __builtin_amdgcn_sched_barrier(0);
    #pragma unroll
    for (int n2 = 0; n2 < 4; n2++){
      f32x4 z = (f32x4){0.f, 0.f, 0.f, 0.f};
      z = MFMA16(qr_[0], rhf[0][n2], z);
      z = MFMA16(qr_[1], rhf[1][n2], z);
      int tp = n2 * 16 + lc;
      uint2 pr; pr.x = pk2(z[0], z[1]); pr.y = pk2(z[2], z[3]);
      *(uint2*)((char*)&Pbd[w][cur][0] + tp * 32 + ((lr * 8) ^ (((tp >> 2) & 3) << 3))) = pr;
    }
    __builtin_amdgcn_s_setprio(0);
    asm volatile("s_waitcnt lgkmcnt(0)" ::: "memory");
    __builtin_amdgcn_sched_barrier(0);

    // 9. sheared BD pickup + online softmax (DPP reductions)
    const char* pbC = (const char*)&Pbd[w][cur][0];
    const char* pbP = (const char*)&Pbd[w][nxt][0];
    const bool maskT = (jt >= jtiles - 2);
    const int mdw = i0 + MLEN - j0 + w * 16;   // mask when dd > mdw  (j > i+MLEN)
    float nm[4];
    #pragma unroll
    for (int e = 0; e < 4; e++){
      int r = lr * 4 + e;
      float tm = -3.0e38f;
      #pragma unroll
      for (int n = 0; n < 4; n++){
        int dd = n * 16 + lc - r;              // jl - r  in [-15, 63]
        int tp = dd & 63;
        const char* base = (n == 0) ? (dd < 0 ? pbP : pbC) : pbC;
        u16 bd = *(const u16*)(base + tp * 32 + ((r * 2) ^ (((tp >> 2) & 3) << 3)));
        float x = (s[n][e] + b2f(bd)) * 0.125f;
        if (maskT && dd > mdw) x = -1.0e30f;
        s[n][e] = x;
        tm = fmaxf(tm, x);
      }
      tm = dppmax<0x121>(tm); tm = dppmax<0x122>(tm);
      tm = dppmax<0x124>(tm); tm = dppmax<0x128>(tm);
      nm[e] = fmaxf(mx[e], tm);
    }
    bool need = (nm[0] > mx[0]) | (nm[1] > mx[1]) | (nm[2] > mx[2]) | (nm[3] > mx[3]);
    if (__any(need)){
      #pragma unroll
      for (int e = 0; e < 4; e++){
        float fc = __expf(mx[e] - nm[e]);
        mx[e] = nm[e];
        sm[e] *= fc;
        #pragma unroll
        for (int df = 0; df < 4; df++) O[df][e] *= fc;
      }
    }
    #pragma unroll
    for (int e = 0; e < 4; e++){
      float ps = 0.f;
      #pragma unroll
      for (int n = 0; n < 4; n++){
        float pv = __expf(s[n][e] - mx[e]);
        s[n][e] = pv;
        ps += pv;
      }
      ps = dppadd<0x121>(ps); ps = dppadd<0x122>(ps);
      ps = dppadd<0x124>(ps); ps = dppadd<0x128>(ps);
      sm[e] += ps;
    }
    // 10. P -> LDS (bf16)
    #pragma unroll
    for (int n = 0; n < 4; n++)
      #pragma unroll
      for (int e = 0; e < 4; e++)
        *(u16*)((char*)&Pt[w][0] + swz(lr * 4 + e, (n * 16 + lc) * 2)) = f2bn(s[n][e]);
    asm volatile("s_waitcnt lgkmcnt(0)" ::: "memory");
    __builtin_amdgcn_sched_barrier(0);

    // 11. O += P @ V
    bf16x8 pa0 = *(const bf16x8*)((const char*)&Pt[w][0] + swz(lc, lr * 16));
    bf16x8 pa1 = *(const bf16x8*)((const char*)&Pt[w][0] + swz(lc, 64 + lr * 16));
    __builtin_amdgcn_s_setprio(1);
    #pragma unroll
    for (int df = 0; df < 4; df++){
      bf16x8 v0 = *(const bf16x8*)((const char*)&Vt[cur][0] + swz(df * 16 + lc, lr * 16));
      bf16x8 v1 = *(const bf16x8*)((const char*)&Vt[cur][0] + swz(df * 16 + lc, 64 + lr * 16));
      O[df] = MFMA16(pa0, v0, O[df]);
      O[df] = MFMA16(pa1, v1, O[df]);
    }
    __builtin_amdgcn_s_setprio(0);
    // 12. all reads of [cur] done before next iteration stages into it
    __builtin_amdgcn_s_barrier();
  }

  asm volatile("s_waitcnt vmcnt(0)" ::: "memory");

  #pragma unroll
  for (int e = 0; e < 4; e++){
    float is = 1.0f / sm[e];
    #pragma unroll
    for (int df = 0; df < 4; df++){
      int i = i0 + w * 16 + lr * 4 + e;
      av[(size_t)(i * BSZ + b) * DM + h * DH + df * 16 + lc] = f2bn(O[df][e] * is);
    }
  }
}

// ---------------- residual + LayerNorm ----------------

__global__ __launch_bounds__(256) void ln_k(const float* __restrict__ w,
                                            const float* __restrict__ ao,
                                            const float* __restrict__ gam,
                                            const float* __restrict__ bet,
                                            float* __restrict__ out){
  __shared__ float red[8];
  const int rw = blockIdx.x, t = threadIdx.x, lane = t & 63, wv = t >> 6;
  const float* wr_ = w + (size_t)rw * DM;
  const float* ar_ = ao + (size_t)rw * DM;
  float x[4];
  float s = 0.f, ss = 0.f;
  #pragma unroll
  for (int k2 = 0; k2 < 4; k2++){
    int c = t + k2 * 256;
    float xv = wr_[c] + ar_[c];
    x[k2] = xv; s += xv; ss += xv * xv;
  }
  #pragma unroll
  for (int m2 = 1; m2 < 64; m2 <<= 1){ s += __shfl_xor(s, m2); ss += __shfl_xor(ss, m2); }
  if (lane == 0){ red[wv] = s; red[4 + wv] = ss; }
  __syncthreads();
  s  = red[0] + red[1] + red[2] + red[3];
  ss = red[4] + red[5] + red[6] + red[7];
  float mu = s * (1.f / DM);
  float var = ss * (1.f / DM) - mu * mu;
  float rs = rsqrtf(var + 1e-5f);
  #pragma unroll
  for (int k2 = 0; k2 < 4; k2++){
    int c = t + k2 * 256;
    out[(size_t)rw * DM + c] = (x[k2] - mu) * rs * gam[c] + bet[c];
  }
}

// ---------------- launch ----------------

extern "C" void kernel_launch(void* const* d_in, const int* in_sizes, int n_in,
                              void* d_out, int out_size, void* d_ws, size_t ws_size,
                              hipStream_t stream)
{
  (void)in_sizes; (void)n_in; (void)out_size; (void)ws_size;
  const float* w    = (const float*)d_in[0];
  const float* r    = (const float*)d_in[1];
  const float* mems = (const float*)d_in[2];
  const float* Wqkv = (const float*)d_in[3];
  const float* Wr   = (const float*)d_in[4];
  const float* Wo   = (const float*)d_in[5];
  const float* rwb  = (const float*)d_in[6];
  const float* rrb  = (const float*)d_in[7];
  const float* gam  = (const float*)d_in[8];
  const float* bet  = (const float*)d_in[9];
  float* out = (float*)d_out;

  char* ws = (char*)d_ws;
  size_t off = 0;
  auto alloc = [&](size_t n){ char* p = ws + off; off += (n + 255) & ~(size_t)255; return p; };
  u16* catB  = (u16*)alloc((size_t)KLEN * BSZ * DM * 2);
  u16* rB    = (u16*)alloc((size_t)KLEN * DM * 2);
  u16* WqkvT = (u16*)alloc((size_t)3 * DM * DM * 2);
  u16* WrT   = (u16*)alloc((size_t)DM * DM * 2);
  u16* WoT   = (u16*)alloc((size_t)DM * DM * 2);
  u16* qBuf  = (u16*)alloc((size_t)BSZ * NH * QLEN * DH * 2);
  u16* kBp   = (u16*)alloc((size_t)BSZ * NH * KLEN * DH * 2);
  u16* vBp   = (u16*)alloc((size_t)BSZ * NH * KLEN * DH * 2);   // d-major
  u16* rhB   = (u16*)alloc((size_t)NH * KLEN * DH * 2);
  u16* av    = (u16*)alloc((size_t)QLEN * BSZ * DM * 2);
  float* ao  = (float*)alloc((size_t)QLEN * BSZ * DM * 4);

  conv_cat<<<dim3(8192), 256, 0, stream>>>(mems, w, catB);
  conv_r<<<dim3(2048), 256, 0, stream>>>(r, rB);
  transpose_conv<<<dim3(96, 32), 256, 0, stream>>>(Wqkv, WqkvT, DM, 3 * DM);
  transpose_conv<<<dim3(32, 32), 256, 0, stream>>>(Wr, WrT, DM, DM);
  transpose_conv<<<dim3(32, 32), 256, 0, stream>>>(Wo, WoT, DM, DM);

  // QKV projection: [8192,1024] x [1024,3072]
  gemm_k<0><<<dim3(24, 64), 256, 0, stream>>>(catB, WqkvT, DM, qBuf, kBp, vBp);
  // R projection: [2048,1024] x [1024,1024]
  gemm_k<1><<<dim3(8, 16), 256, 0, stream>>>(rB, WrT, DM, rhB, nullptr, nullptr);

  // fused attention: 512 blocks x 512 threads (2 blocks/CU, 80 KB LDS each)
  attn_k<<<dim3(512), 512, 0, stream>>>(qBuf, kBp, vBp, rhB, rwb, rrb, av);

  // output projection: [4096,1024] x [1024,1024]
  gemm_k<3><<<dim3(8, 32), 256, 0, stream>>>(av, WoT, DM, ao, nullptr, nullptr);
  ln_k<<<dim3(4096), 256, 0, stream>>>(w, ao, gam, bet, out);
}

// Round 6
// 581.494 us; speedup vs baseline: 1.0004x; 1.0004x over previous
//
#include <hip/hip_runtime.h>
#include <hip/hip_bf16.h>
#include <stdint.h>

#define QLEN 1024
#define MLEN 1024
#define KLEN 2048
#define BSZ 4
#define NH 16
#define DH 64
#define DM 1024

typedef __attribute__((ext_vector_type(8))) short bf16x8;
typedef __attribute__((ext_vector_type(4))) float f32x4;
typedef unsigned short u16;
typedef unsigned int u32;

typedef unsigned int __attribute__((address_space(1))) gu32;
typedef unsigned int __attribute__((address_space(3))) lu32;

__device__ __forceinline__ void stage16(const void* g, void* l){
  __builtin_amdgcn_global_load_lds((const gu32*)g, (lu32*)l, 16, 0, 0);
}

__device__ __forceinline__ u16 f2b(float f){
  u32 u = __builtin_bit_cast(u32, f);
  u32 r = (u + 0x7FFFu + ((u >> 16) & 1u)) >> 16;
  return (u16)r;
}
__device__ __forceinline__ float b2f(u16 v){
  u32 u = ((u32)v) << 16;
  return __builtin_bit_cast(float, u);
}
// native converts (compiler emits v_cvt_pk_bf16_f32); bits via memcpy since
// __hip_bfloat16 types are not trivially copyable (no bit_cast).
__device__ __forceinline__ u16 f2bn(float f){
  __hip_bfloat16 h = __float2bfloat16(f);
  u16 r; __builtin_memcpy(&r, &h, 2); return r;
}
__device__ __forceinline__ u32 pk2(float a, float b){
  float2 t; t.x = a; t.y = b;
  __hip_bfloat162 h = __float22bfloat162_rn(t);
  u32 r; __builtin_memcpy(&r, &h, 4); return r;
}

// XOR swizzle for [rows][64]bf16 tiles (128B rows)
__device__ __forceinline__ int swz(int row, int byteoff){
  return (row << 7) + (byteoff ^ (((row ^ (row >> 3)) & 7) << 4));
}

// DPP 16-lane-row reductions (row_ror:N = 0x120+N)
template<int C>
__device__ __forceinline__ float dppmax(float x){
  int t = __builtin_amdgcn_update_dpp(0, __builtin_bit_cast(int, x), C, 0xf, 0xf, true);
  return fmaxf(x, __builtin_bit_cast(float, t));
}
template<int C>
__device__ __forceinline__ float dppadd(float x){
  int t = __builtin_amdgcn_update_dpp(0, __builtin_bit_cast(int, x), C, 0xf, 0xf, true);
  return x + __builtin_bit_cast(float, t);
}

#define MFMA16(a, b, c) __builtin_amdgcn_mfma_f32_16x16x32_bf16(a, b, c, 0, 0, 0)

// ---------------- conversion kernels ----------------

__global__ __launch_bounds__(256) void conv_cat(const float* __restrict__ mems,
                                                const float* __restrict__ w,
                                                u16* __restrict__ dst){
  int idx = blockIdx.x * 256 + threadIdx.x;
  const int memf4 = MLEN * BSZ * DM / 4;
  float4 v = (idx < memf4) ? ((const float4*)mems)[idx]
                           : ((const float4*)w)[idx - memf4];
  ushort4 o;
  o.x = f2b(v.x); o.y = f2b(v.y); o.z = f2b(v.z); o.w = f2b(v.w);
  ((ushort4*)dst)[idx] = o;
}

__global__ __launch_bounds__(256) void conv_r(const float* __restrict__ r,
                                              u16* __restrict__ dst){
  int idx = blockIdx.x * 256 + threadIdx.x;
  float4 v = ((const float4*)r)[idx];
  ushort4 o;
  o.x = f2b(v.x); o.y = f2b(v.y); o.z = f2b(v.z); o.w = f2b(v.w);
  ((ushort4*)dst)[idx] = o;
}

__global__ __launch_bounds__(256) void transpose_conv(const float* __restrict__ src,
                                                      u16* __restrict__ dst,
                                                      int R, int C){
  __shared__ float tile[32][33];
  int c0 = blockIdx.x * 32, r0 = blockIdx.y * 32;
  int tx = threadIdx.x & 31, ty = threadIdx.x >> 5;
  #pragma unroll
  for (int rr = ty; rr < 32; rr += 8)
    tile[rr][tx] = src[(size_t)(r0 + rr) * C + c0 + tx];
  __syncthreads();
  #pragma unroll
  for (int rr = ty; rr < 32; rr += 8)
    dst[(size_t)(c0 + rr) * R + r0 + tx] = f2b(tile[tx][rr]);
}

// ---------------- generic bf16 MFMA GEMM (128x128 tile, BK=32) ----------------
// MODE 0: QKV projection epilogue (q raw [bh][t][d]; k [bh][t][d]; v d-major [bh][d][t])
// MODE 1: R projection epilogue (rh in [h][t][d])
// MODE 3: plain f32 row-major C

template<int MODE>
__global__ __launch_bounds__(256, 2) void gemm_k(
    const u16* __restrict__ A, const u16* __restrict__ Bt, int K,
    void* __restrict__ o0, void* __restrict__ o1, void* __restrict__ o2)
{
  __shared__ u16 As[128 * 32];
  __shared__ u16 Bs[128 * 32];
  const int tid = threadIdx.x;
  const int lane = tid & 63, w = tid >> 6;
  const int wr = w >> 1, wc = w & 1;
  const int lr = lane >> 4, lc = lane & 15;
  const int m0 = blockIdx.y * 128, n0 = blockIdx.x * 128;

  f32x4 acc[4][4];
  #pragma unroll
  for (int i = 0; i < 4; i++)
    #pragma unroll
    for (int j = 0; j < 4; j++)
      acc[i][j] = (f32x4){0.f, 0.f, 0.f, 0.f};

  for (int k0 = 0; k0 < K; k0 += 32){
    #pragma unroll
    for (int rnd = 0; rnd < 2; rnd++){
      int c = rnd * 256 + w * 64 + lane;
      int row = c >> 2, kc = c & 3;
      stage16((const char*)A + ((size_t)(m0 + row) * K + k0 + kc * 8) * 2,
              (char*)As + (rnd * 256 + w * 64) * 16);
      stage16((const char*)Bt + ((size_t)(n0 + row) * K + k0 + kc * 8) * 2,
              (char*)Bs + (rnd * 256 + w * 64) * 16);
    }
    asm volatile("s_waitcnt vmcnt(0)");
    __syncthreads();

    bf16x8 af[4], bfr[4];
    #pragma unroll
    for (int mf = 0; mf < 4; mf++)
      af[mf] = *(const bf16x8*)((const char*)As + (wr * 64 + mf * 16 + lc) * 64 + lr * 16);
    #pragma unroll
    for (int nf = 0; nf < 4; nf++)
      bfr[nf] = *(const bf16x8*)((const char*)Bs + (wc * 64 + nf * 16 + lc) * 64 + lr * 16);
    #pragma unroll
    for (int mf = 0; mf < 4; mf++)
      #pragma unroll
      for (int nf = 0; nf < 4; nf++)
        acc[mf][nf] = MFMA16(af[mf], bfr[nf], acc[mf][nf]);
    __syncthreads();
  }

  #pragma unroll
  for (int mf = 0; mf < 4; mf++){
    #pragma unroll
    for (int nf = 0; nf < 4; nf++){
      #pragma unroll
      for (int e = 0; e < 4; e++){
        float v = acc[mf][nf][e];
        int row = m0 + wr * 64 + mf * 16 + lr * 4 + e;
        int col = n0 + wc * 64 + nf * 16 + lc;
        if constexpr (MODE == 0){
          int t = row >> 2, bb = row & 3;
          int s = col >> 10, rem = col & 1023;
          int h = rem >> 6, d = rem & 63;
          if (s == 0){
            if (t >= MLEN)
              ((u16*)o0)[((size_t)(bb * NH + h) * QLEN + (t - MLEN)) * DH + d] = f2b(v);
          } else if (s == 1){
            ((u16*)o1)[((size_t)(bb * NH + h) * KLEN + t) * DH + d] = f2b(v);    // k [bh][t][d]
          } else {
            ((u16*)o2)[((size_t)(bb * NH + h) * DH + d) * KLEN + t] = f2b(v);    // v [bh][d][t]
          }
        } else if constexpr (MODE == 1){
          int h = col >> 6, d = col & 63;
          ((u16*)o0)[((size_t)h * KLEN + row) * DH + d] = f2b(v);
        } else {
          ((float*)o0)[(size_t)row * DM + col] = v;
        }
      }
    }
  }
}

// ---------------- fused flash attention, 128-row blocks, 8 waves ----------------
// Per wave: 16 q-rows. BD band per wave starts at t0-16w so the sheared pickup
// index (jl - r) & 63 is wave-independent. K/V staged via global_load_lds
// (V stored d-major by the GEMM); rh B-fragments loaded per-lane from global
// (L2-resident). Counted vmcnt, raw barriers, exact defer-rescale.
// XCD decode: XCD k owns heads {2k,2k+1} x all b x all i-blocks, so the
// co-resident working set per XCD (rh 512KB + lockstep K/V tiles) fits L2.

__global__ __launch_bounds__(512, 4) void attn_k(
    const u16* __restrict__ qB,  const u16* __restrict__ kB,
    const u16* __restrict__ vB,  const u16* __restrict__ rhB,
    const float* __restrict__ rwb, const float* __restrict__ rrb,
    u16* __restrict__ av)
{
  __shared__ u16 Kt[2][64 * 64];      // [j][d] swizzled          16 KB
  __shared__ u16 Vt[2][64 * 64];      // [d][j] swizzled          16 KB
  __shared__ u16 Pt[8][16 * 64];      // per-wave P [row][j] swz  16 KB
  __shared__ u16 Pbd[8][2][64 * 16];  // per-wave BD [t'][r] oct-XOR, parity dbuf  32 KB

  const int tid = threadIdx.x, lane = tid & 63, w = tid >> 6;
  const int lr = lane >> 4, lc = lane & 15;

  // nid: 64 consecutive ids per XCD (bid%8 = XCD). Decode: 2 heads per XCD,
  // all 4 batches, 8 i-blocks (balanced pairing (0,7),(1,6),(2,5),(3,4)).
  const int bid = blockIdx.x;
  const int nid = (bid & 7) * 64 + (bid >> 3);
  const int local = nid & 63;
  const int h  = (nid >> 6) * 2 + (local >> 5);
  const int b  = (local >> 3) & 3;
  const int tt = local & 7;
  const int iblk = (tt & 1) ? (7 - (tt >> 1)) : (tt >> 1);
  const int i0 = iblk * 128;
  const size_t bh = (size_t)b * NH + h;

  // staging constants: 512 threads cover one 64x64 bf16 tile (8 KB)
  const int srow = tid >> 3;
  const int sch  = (tid & 7) ^ ((srow ^ (srow >> 3)) & 7);

  // Q A-fragments with biases (rows i0 + w*16 + lc)
  bf16x8 qw_[2], qr_[2];
  #pragma unroll
  for (int ks = 0; ks < 2; ks++){
    bf16x8 qv = *(const bf16x8*)(qB + (bh * QLEN + i0 + w * 16 + lc) * DH + ks * 32 + lr * 8);
    #pragma unroll
    for (int e2 = 0; e2 < 8; e2++){
      int d = ks * 32 + lr * 8 + e2;
      float q32 = b2f((u16)qv[e2]);
      qw_[ks][e2] = (short)f2bn(q32 + rwb[h * DH + d]);
      qr_[ks][e2] = (short)f2bn(q32 + rrb[h * DH + d]);
    }
  }

  f32x4 O[4];
  float mx[4], sm[4];
  #pragma unroll
  for (int df = 0; df < 4; df++) O[df] = (f32x4){0.f, 0.f, 0.f, 0.f};
  #pragma unroll
  for (int e = 0; e < 4; e++){ mx[e] = -3.0e38f; sm[e] = 0.f; }

  const char* kgb = (const char*)(kB + bh * (size_t)KLEN * DH);
  const char* vgb = (const char*)(vB + bh * (size_t)KLEN * DH);   // [DH][KLEN]
  const char* rgb = (const char*)(rhB + (size_t)h * KLEN * DH);

  const int jtiles = (i0 >> 6) + 18;
  const int twbase = 1023 - i0 - 16 * w;   // per-wave band origin at j0=0

  bf16x8 rhf[2][4];

  // ---- prologue: prev band BD -> Pbd[w][1]; stage tile 0 ----
  {
    #pragma unroll
    for (int ks = 0; ks < 2; ks++)
      #pragma unroll
      for (int n2 = 0; n2 < 4; n2++){
        int t = twbase - 64 + n2 * 16 + lc; t = t < 0 ? 0 : t;
        rhf[ks][n2] = *(const bf16x8*)(rgb + (size_t)t * 128 + ks * 64 + lr * 16);
      }
    __builtin_amdgcn_sched_barrier(0);
    stage16(kgb + (size_t)srow * 128 + sch * 16, (char*)&Kt[0][0] + tid * 16);
    stage16(vgb + (size_t)srow * 4096 + sch * 16, (char*)&Vt[0][0] + tid * 16);
    __builtin_amdgcn_sched_barrier(0);
    asm volatile("s_waitcnt vmcnt(2)" ::: "memory");
    __builtin_amdgcn_sched_barrier(0);
    #pragma unroll
    for (int n2 = 0; n2 < 4; n2++){
      f32x4 z = (f32x4){0.f, 0.f, 0.f, 0.f};
      z = MFMA16(qr_[0], rhf[0][n2], z);
      z = MFMA16(qr_[1], rhf[1][n2], z);
      int tp = n2 * 16 + lc;
      uint2 pr; pr.x = pk2(z[0], z[1]); pr.y = pk2(z[2], z[3]);
      *(uint2*)((char*)&Pbd[w][1][0] + tp * 32 + ((lr * 8) ^ (((tp >> 2) & 3) << 3))) = pr;
    }
  }

  for (int jt = 0; jt < jtiles; jt++){
    const int j0 = jt * 64;
    const int cur = jt & 1, nxt = cur ^ 1;
    const int tw0 = twbase + j0;

    // 1. rh loads for current band (8 in flight)
    #pragma unroll
    for (int ks = 0; ks < 2; ks++)
      #pragma unroll
      for (int n2 = 0; n2 < 4; n2++){
        int t = tw0 + n2 * 16 + lc; t = t > 2047 ? 2047 : t;
        rhf[ks][n2] = *(const bf16x8*)(rgb + (size_t)t * 128 + ks * 64 + lr * 16);
      }
    __builtin_amdgcn_sched_barrier(0);
    // 2. stage next K/V tiles (into [nxt]); last iter restages current (harmless)
    {
      int jn = (jt + 1 < jtiles) ? j0 + 64 : j0;
      stage16(kgb + (size_t)(jn + srow) * 128 + sch * 16, (char*)&Kt[nxt][0] + tid * 16);
      stage16(vgb + (size_t)srow * 4096 + jn * 2 + sch * 16, (char*)&Vt[nxt][0] + tid * 16);
    }
    __builtin_amdgcn_sched_barrier(0);
    // 3+4. wait current-tile stages (8 rh + 2 nxt stages stay in flight), sync
    asm volatile("s_waitcnt vmcnt(10)" ::: "memory");
    __builtin_amdgcn_s_barrier();

    // 5. AC = (q + r_w_bias) K^T
    f32x4 s[4];
    __builtin_amdgcn_s_setprio(1);
    #pragma unroll
    for (int n = 0; n < 4; n++){
      bf16x8 k0f = *(const bf16x8*)((const char*)&Kt[cur][0] + swz(n * 16 + lc, lr * 16));
      bf16x8 k1f = *(const bf16x8*)((const char*)&Kt[cur][0] + swz(n * 16 + lc, 64 + lr * 16));
      f32x4 z = (f32x4){0.f, 0.f, 0.f, 0.f};
      z = MFMA16(qw_[0], k0f, z);
      z = MFMA16(qw_[1], k1f, z);
      s[n] = z;
    }
    // 6+7. BD band -> Pbd[w][cur] (b64 writes via cvt_pk)
    asm volatile("s_waitcnt vmcnt(2)" ::: "memory");
    __builtin_amdgcn_sched_barrier(0);
    #pragma unroll
    for (int n2 = 0; n2 < 4; n2++){
      f32x4 z = (f32x4){0.f, 0.f, 0.f, 0.f};
      z = MFMA16(qr_[0], rhf[0][n2], z);
      z = MFMA16(qr_[1], rhf[1][n2], z);
      int tp = n2 * 16 + lc;
      uint2 pr; pr.x = pk2(z[0], z[1]); pr.y = pk2(z[2], z[3]);
      *(uint2*)((char*)&Pbd[w][cur][0] + tp * 32 + ((lr * 8) ^ (((tp >> 2) & 3) << 3))) = pr;
    }
    __builtin_amdgcn_s_setprio(0);
    asm volatile("s_waitcnt lgkmcnt(0)" ::: "memory");
    __builtin_amdgcn_sched_barrier(0);

    // 9. sheared BD pickup + online softmax (DPP reductions)
    const char* pbC = (const char*)&Pbd[w][cur][0];
    const char* pbP = (const char*)&Pbd[w][nxt][0];
    const bool maskT = (jt >= jtiles - 2);
    const int mdw = i0 + MLEN - j0 + w * 16;   // mask when dd > mdw  (j > i+MLEN)
    float nm[4];
    #pragma unroll
    for (int e = 0; e < 4; e++){
      int r = lr * 4 + e;
      float tm = -3.0e38f;
      #pragma unroll
      for (int n = 0; n < 4; n++){
        int dd = n * 16 + lc - r;              // jl - r  in [-15, 63]
        int tp = dd & 63;
        const char* base = (n == 0) ? (dd < 0 ? pbP : pbC) : pbC;
        u16 bd = *(const u16*)(base + tp * 32 + ((r * 2) ^ (((tp >> 2) & 3) << 3)));
        float x = (s[n][e] + b2f(bd)) * 0.125f;
        if (maskT && dd > mdw) x = -1.0e30f;
        s[n][e] = x;
        tm = fmaxf(tm, x);
      }
      tm = dppmax<0x121>(tm); tm = dppmax<0x122>(tm);
      tm = dppmax<0x124>(tm); tm = dppmax<0x128>(tm);
      nm[e] = fmaxf(mx[e], tm);
    }
    bool need = (nm[0] > mx[0]) | (nm[1] > mx[1]) | (nm[2] > mx[2]) | (nm[3] > mx[3]);
    if (__any(need)){
      #pragma unroll
      for (int e = 0; e < 4; e++){
        float fc = __expf(mx[e] - nm[e]);
        mx[e] = nm[e];
        sm[e] *= fc;
        #pragma unroll
        for (int df = 0; df < 4; df++) O[df][e] *= fc;
      }
    }
    #pragma unroll
    for (int e = 0; e < 4; e++){
      float ps = 0.f;
      #pragma unroll
      for (int n = 0; n < 4; n++){
        float pv = __expf(s[n][e] - mx[e]);
        s[n][e] = pv;
        ps += pv;
      }
      ps = dppadd<0x121>(ps); ps = dppadd<0x122>(ps);
      ps = dppadd<0x124>(ps); ps = dppadd<0x128>(ps);
      sm[e] += ps;
    }
    // 10. P -> LDS (bf16)
    #pragma unroll
    for (int n = 0; n < 4; n++)
      #pragma unroll
      for (int e = 0; e < 4; e++)
        *(u16*)((char*)&Pt[w][0] + swz(lr * 4 + e, (n * 16 + lc) * 2)) = f2bn(s[n][e]);
    asm volatile("s_waitcnt lgkmcnt(0)" ::: "memory");
    __builtin_amdgcn_sched_barrier(0);

    // 11. O += P @ V
    bf16x8 pa0 = *(const bf16x8*)((const char*)&Pt[w][0] + swz(lc, lr * 16));
    bf16x8 pa1 = *(const bf16x8*)((const char*)&Pt[w][0] + swz(lc, 64 + lr * 16));
    __builtin_amdgcn_s_setprio(1);
    #pragma unroll
    for (int df = 0; df < 4; df++){
      bf16x8 v0 = *(const bf16x8*)((const char*)&Vt[cur][0] + swz(df * 16 + lc, lr * 16));
      bf16x8 v1 = *(const bf16x8*)((const char*)&Vt[cur][0] + swz(df * 16 + lc, 64 + lr * 16));
      O[df] = MFMA16(pa0, v0, O[df]);
      O[df] = MFMA16(pa1, v1, O[df]);
    }
    __builtin_amdgcn_s_setprio(0);
    // 12. all reads of [cur] done before next iteration stages into it
    __builtin_amdgcn_s_barrier();
  }

  asm volatile("s_waitcnt vmcnt(0)" ::: "memory");

  #pragma unroll
  for (int e = 0; e < 4; e++){
    float is = 1.0f / sm[e];
    #pragma unroll
    for (int df = 0; df < 4; df++){
      int i = i0 + w * 16 + lr * 4 + e;
      av[(size_t)(i * BSZ + b) * DM + h * DH + df * 16 + lc] = f2bn(O[df][e] * is);
    }
  }
}

// ---------------- residual + LayerNorm ----------------

__global__ __launch_bounds__(256) void ln_k(const float* __restrict__ w,
                                            const float* __restrict__ ao,
                                            const float* __restrict__ gam,
                                            const float* __restrict__ bet,
                                            float* __restrict__ out){
  __shared__ float red[8];
  const int rw = blockIdx.x, t = threadIdx.x, lane = t & 63, wv = t >> 6;
  const float* wr_ = w + (size_t)rw * DM;
  const float* ar_ = ao + (size_t)rw * DM;
  float x[4];
  float s = 0.f, ss = 0.f;
  #pragma unroll
  for (int k2 = 0; k2 < 4; k2++){
    int c = t + k2 * 256;
    float xv = wr_[c] + ar_[c];
    x[k2] = xv; s += xv; ss += xv * xv;
  }
  #pragma unroll
  for (int m2 = 1; m2 < 64; m2 <<= 1){ s += __shfl_xor(s, m2); ss += __shfl_xor(ss, m2); }
  if (lane == 0){ red[wv] = s; red[4 + wv] = ss; }
  __syncthreads();
  s  = red[0] + red[1] + red[2] + red[3];
  ss = red[4] + red[5] + red[6] + red[7];
  float mu = s * (1.f / DM);
  float var = ss * (1.f / DM) - mu * mu;
  float rs = rsqrtf(var + 1e-5f);
  #pragma unroll
  for (int k2 = 0; k2 < 4; k2++){
    int c = t + k2 * 256;
    out[(size_t)rw * DM + c] = (x[k2] - mu) * rs * gam[c] + bet[c];
  }
}

// ---------------- launch ----------------

extern "C" void kernel_launch(void* const* d_in, const int* in_sizes, int n_in,
                              void* d_out, int out_size, void* d_ws, size_t ws_size,
                              hipStream_t stream)
{
  (void)in_sizes; (void)n_in; (void)out_size; (void)ws_size;
  const float* w    = (const float*)d_in[0];
  const float* r    = (const float*)d_in[1];
  const float* mems = (const float*)d_in[2];
  const float* Wqkv = (const float*)d_in[3];
  const float* Wr   = (const float*)d_in[4];
  const float* Wo   = (const float*)d_in[5];
  const float* rwb  = (const float*)d_in[6];
  const float* rrb  = (const float*)d_in[7];
  const float* gam  = (const float*)d_in[8];
  const float* bet  = (const float*)d_in[9];
  float* out = (float*)d_out;

  char* ws = (char*)d_ws;
  size_t off = 0;
  auto alloc = [&](size_t n){ char* p = ws + off; off += (n + 255) & ~(size_t)255; return p; };
  u16* catB  = (u16*)alloc((size_t)KLEN * BSZ * DM * 2);
  u16* rB    = (u16*)alloc((size_t)KLEN * DM * 2);
  u16* WqkvT = (u16*)alloc((size_t)3 * DM * DM * 2);
  u16* WrT   = (u16*)alloc((size_t)DM * DM * 2);
  u16* WoT   = (u16*)alloc((size_t)DM * DM * 2);
  u16* qBuf  = (u16*)alloc((size_t)BSZ * NH * QLEN * DH * 2);
  u16* kBp   = (u16*)alloc((size_t)BSZ * NH * KLEN * DH * 2);
  u16* vBp   = (u16*)alloc((size_t)BSZ * NH * KLEN * DH * 2);   // d-major
  u16* rhB   = (u16*)alloc((size_t)NH * KLEN * DH * 2);
  u16* av    = (u16*)alloc((size_t)QLEN * BSZ * DM * 2);
  float* ao  = (float*)alloc((size_t)QLEN * BSZ * DM * 4);

  conv_cat<<<dim3(8192), 256, 0, stream>>>(mems, w, catB);
  conv_r<<<dim3(2048), 256, 0, stream>>>(r, rB);
  transpose_conv<<<dim3(96, 32), 256, 0, stream>>>(Wqkv, WqkvT, DM, 3 * DM);
  transpose_conv<<<dim3(32, 32), 256, 0, stream>>>(Wr, WrT, DM, DM);
  transpose_conv<<<dim3(32, 32), 256, 0, stream>>>(Wo, WoT, DM, DM);

  // QKV projection: [8192,1024] x [1024,3072]
  gemm_k<0><<<dim3(24, 64), 256, 0, stream>>>(catB, WqkvT, DM, qBuf, kBp, vBp);
  // R projection: [2048,1024] x [1024,1024]
  gemm_k<1><<<dim3(8, 16), 256, 0, stream>>>(rB, WrT, DM, rhB, nullptr, nullptr);

  // fused attention: 512 blocks x 512 threads (2 blocks/CU, 80 KB LDS each)
  attn_k<<<dim3(512), 512, 0, stream>>>(qBuf, kBp, vBp, rhB, rwb, rrb, av);

  // output projection: [4096,1024] x [1024,1024]
  gemm_k<3><<<dim3(8, 32), 256, 0, stream>>>(av, WoT, DM, ao, nullptr, nullptr);
  ln_k<<<dim3(4096), 256, 0, stream>>>(w, ao, gam, bet, out);
}

// Round 7
// 309.580 us; speedup vs baseline: 1.8790x; 1.8783x over previous
//
#include <hip/hip_runtime.h>
#include <hip/hip_bf16.h>
#include <stdint.h>

#define QLEN 1024
#define MLEN 1024
#define KLEN 2048
#define BSZ 4
#define NH 16
#define DH 64
#define DM 1024

typedef __attribute__((ext_vector_type(8))) short bf16x8;
typedef __attribute__((ext_vector_type(4))) float f32x4;
typedef unsigned short u16;
typedef unsigned int u32;

typedef unsigned int __attribute__((address_space(1))) gu32;
typedef unsigned int __attribute__((address_space(3))) lu32;

__device__ __forceinline__ void stage16(const void* g, void* l){
  __builtin_amdgcn_global_load_lds((const gu32*)g, (lu32*)l, 16, 0, 0);
}

__device__ __forceinline__ u16 f2b(float f){
  u32 u = __builtin_bit_cast(u32, f);
  u32 r = (u + 0x7FFFu + ((u >> 16) & 1u)) >> 16;
  return (u16)r;
}
__device__ __forceinline__ float b2f(u16 v){
  u32 u = ((u32)v) << 16;
  return __builtin_bit_cast(float, u);
}
// native converts (compiler emits v_cvt_pk_bf16_f32); bits via memcpy since
// __hip_bfloat16 types are not trivially copyable (no bit_cast).
__device__ __forceinline__ u16 f2bn(float f){
  __hip_bfloat16 h = __float2bfloat16(f);
  u16 r; __builtin_memcpy(&r, &h, 2); return r;
}
__device__ __forceinline__ u32 pk2(float a, float b){
  float2 t; t.x = a; t.y = b;
  __hip_bfloat162 h = __float22bfloat162_rn(t);
  u32 r; __builtin_memcpy(&r, &h, 4); return r;
}

// XOR swizzle for [rows][64]bf16 tiles (128B rows)
__device__ __forceinline__ int swz(int row, int byteoff){
  return (row << 7) + (byteoff ^ (((row ^ (row >> 3)) & 7) << 4));
}

// DPP 16-lane-row reductions (row_ror:N = 0x120+N)
template<int C>
__device__ __forceinline__ float dppmax(float x){
  int t = __builtin_amdgcn_update_dpp(0, __builtin_bit_cast(int, x), C, 0xf, 0xf, true);
  return fmaxf(x, __builtin_bit_cast(float, t));
}
template<int C>
__device__ __forceinline__ float dppadd(float x){
  int t = __builtin_amdgcn_update_dpp(0, __builtin_bit_cast(int, x), C, 0xf, 0xf, true);
  return x + __builtin_bit_cast(float, t);
}

#define MFMA16(a, b, c) __builtin_amdgcn_mfma_f32_16x16x32_bf16(a, b, c, 0, 0, 0)

// ---------------- conversion kernels ----------------

__global__ __launch_bounds__(256) void conv_cat(const float* __restrict__ mems,
                                                const float* __restrict__ w,
                                                u16* __restrict__ dst){
  int idx = blockIdx.x * 256 + threadIdx.x;
  const int memf4 = MLEN * BSZ * DM / 4;
  float4 v = (idx < memf4) ? ((const float4*)mems)[idx]
                           : ((const float4*)w)[idx - memf4];
  ushort4 o;
  o.x = f2b(v.x); o.y = f2b(v.y); o.z = f2b(v.z); o.w = f2b(v.w);
  ((ushort4*)dst)[idx] = o;
}

__global__ __launch_bounds__(256) void conv_r(const float* __restrict__ r,
                                              u16* __restrict__ dst){
  int idx = blockIdx.x * 256 + threadIdx.x;
  float4 v = ((const float4*)r)[idx];
  ushort4 o;
  o.x = f2b(v.x); o.y = f2b(v.y); o.z = f2b(v.z); o.w = f2b(v.w);
  ((ushort4*)dst)[idx] = o;
}

__global__ __launch_bounds__(256) void transpose_conv(const float* __restrict__ src,
                                                      u16* __restrict__ dst,
                                                      int R, int C){
  __shared__ float tile[32][33];
  int c0 = blockIdx.x * 32, r0 = blockIdx.y * 32;
  int tx = threadIdx.x & 31, ty = threadIdx.x >> 5;
  #pragma unroll
  for (int rr = ty; rr < 32; rr += 8)
    tile[rr][tx] = src[(size_t)(r0 + rr) * C + c0 + tx];
  __syncthreads();
  #pragma unroll
  for (int rr = ty; rr < 32; rr += 8)
    dst[(size_t)(c0 + rr) * R + r0 + tx] = f2b(tile[tx][rr]);
}

// ---------------- generic bf16 MFMA GEMM (128x128 tile, BK=32) ----------------
// MODE 0: QKV projection epilogue (q raw [bh][t][d]; k [bh][t][d]; v d-major [bh][d][t])
// MODE 1: R projection epilogue (rh in [h][t][d])
// MODE 3: plain f32 row-major C

template<int MODE>
__global__ __launch_bounds__(256, 2) void gemm_k(
    const u16* __restrict__ A, const u16* __restrict__ Bt, int K,
    void* __restrict__ o0, void* __restrict__ o1, void* __restrict__ o2)
{
  __shared__ u16 As[128 * 32];
  __shared__ u16 Bs[128 * 32];
  const int tid = threadIdx.x;
  const int lane = tid & 63, w = tid >> 6;
  const int wr = w >> 1, wc = w & 1;
  const int lr = lane >> 4, lc = lane & 15;
  const int m0 = blockIdx.y * 128, n0 = blockIdx.x * 128;

  f32x4 acc[4][4];
  #pragma unroll
  for (int i = 0; i < 4; i++)
    #pragma unroll
    for (int j = 0; j < 4; j++)
      acc[i][j] = (f32x4){0.f, 0.f, 0.f, 0.f};

  for (int k0 = 0; k0 < K; k0 += 32){
    #pragma unroll
    for (int rnd = 0; rnd < 2; rnd++){
      int c = rnd * 256 + w * 64 + lane;
      int row = c >> 2, kc = c & 3;
      stage16((const char*)A + ((size_t)(m0 + row) * K + k0 + kc * 8) * 2,
              (char*)As + (rnd * 256 + w * 64) * 16);
      stage16((const char*)Bt + ((size_t)(n0 + row) * K + k0 + kc * 8) * 2,
              (char*)Bs + (rnd * 256 + w * 64) * 16);
    }
    asm volatile("s_waitcnt vmcnt(0)");
    __syncthreads();

    bf16x8 af[4], bfr[4];
    #pragma unroll
    for (int mf = 0; mf < 4; mf++)
      af[mf] = *(const bf16x8*)((const char*)As + (wr * 64 + mf * 16 + lc) * 64 + lr * 16);
    #pragma unroll
    for (int nf = 0; nf < 4; nf++)
      bfr[nf] = *(const bf16x8*)((const char*)Bs + (wc * 64 + nf * 16 + lc) * 64 + lr * 16);
    #pragma unroll
    for (int mf = 0; mf < 4; mf++)
      #pragma unroll
      for (int nf = 0; nf < 4; nf++)
        acc[mf][nf] = MFMA16(af[mf], bfr[nf], acc[mf][nf]);
    __syncthreads();
  }

  #pragma unroll
  for (int mf = 0; mf < 4; mf++){
    #pragma unroll
    for (int nf = 0; nf < 4; nf++){
      #pragma unroll
      for (int e = 0; e < 4; e++){
        float v = acc[mf][nf][e];
        int row = m0 + wr * 64 + mf * 16 + lr * 4 + e;
        int col = n0 + wc * 64 + nf * 16 + lc;
        if constexpr (MODE == 0){
          int t = row >> 2, bb = row & 3;
          int s = col >> 10, rem = col & 1023;
          int h = rem >> 6, d = rem & 63;
          if (s == 0){
            if (t >= MLEN)
              ((u16*)o0)[((size_t)(bb * NH + h) * QLEN + (t - MLEN)) * DH + d] = f2b(v);
          } else if (s == 1){
            ((u16*)o1)[((size_t)(bb * NH + h) * KLEN + t) * DH + d] = f2b(v);    // k [bh][t][d]
          } else {
            ((u16*)o2)[((size_t)(bb * NH + h) * DH + d) * KLEN + t] = f2b(v);    // v [bh][d][t]
          }
        } else if constexpr (MODE == 1){
          int h = col >> 6, d = col & 63;
          ((u16*)o0)[((size_t)h * KLEN + row) * DH + d] = f2b(v);
        } else {
          ((float*)o0)[(size_t)row * DM + col] = v;
        }
      }
    }
  }
}

// ---------------- fused flash attention, 64-row blocks, 4 waves ----------------
// r3 memory pattern (block-shared LDS staging of K, V, rh band; 1024 blocks,
// validated XCD remap -> 28.8MB FETCH) + r5 compute wins (d-major V staging,
// counted vmcnt(6), raw barriers, DPP softmax, native cvt, defer-rescale).
// BD computed swapped: BD^T = mfma(Rb_frag, qr) so Pbd[64 r][64 t'] is written
// with packed b64 stores (row-XOR swizzled). Sheared pickup: Pbd[il][dd&63],
// parity double-buffer for dd<0. Last-tile mask is exactly dd>0.

__global__ __launch_bounds__(256, 2) void attn_k(
    const u16* __restrict__ qB,  const u16* __restrict__ kB,
    const u16* __restrict__ vB,  const u16* __restrict__ rhB,
    const float* __restrict__ rwb, const float* __restrict__ rrb,
    u16* __restrict__ av)
{
  __shared__ u16 Kt[2][64 * 64];      // [j][d] swizzled     16 KB
  __shared__ u16 Vt[2][64 * 64];      // [d][j] swizzled     16 KB
  __shared__ u16 Rb[2][64 * 64];      // band [t'][d] swz    16 KB
  __shared__ u16 Pt[4][16 * 64];      // per-wave P [r][j]    8 KB
  __shared__ u16 Pbd[2][64 * 64];     // BD [r][t'] row-XOR  16 KB   total 72 KB

  const int tid = threadIdx.x, lane = tid & 63, w = tid >> 6;
  const int lr = lane >> 4, lc = lane & 15;

  // r3-validated XCD remap: bid%8 = XCD, i fastest within an XCD's chunk
  const int bid = blockIdx.x;
  const int nid = (bid & 7) * 128 + (bid >> 3);
  const int i0 = (nid & 15) * 64;
  const int h  = (nid >> 4) & 15;
  const int b  = nid >> 8;
  const size_t bh = (size_t)b * NH + h;

  // Q fragments with biases (rows i0 + w*16 + lc)
  bf16x8 qw_[2], qr_[2];
  #pragma unroll
  for (int ks = 0; ks < 2; ks++){
    bf16x8 qv = *(const bf16x8*)(qB + (bh * QLEN + i0 + w * 16 + lc) * DH + ks * 32 + lr * 8);
    #pragma unroll
    for (int e2 = 0; e2 < 8; e2++){
      int d = ks * 32 + lr * 8 + e2;
      float q32 = b2f((u16)qv[e2]);
      qw_[ks][e2] = (short)f2bn(q32 + rwb[h * DH + d]);
      qr_[ks][e2] = (short)f2bn(q32 + rrb[h * DH + d]);
    }
  }

  f32x4 O[4];
  float mx[4], sm[4];
  #pragma unroll
  for (int df = 0; df < 4; df++) O[df] = (f32x4){0.f, 0.f, 0.f, 0.f};
  #pragma unroll
  for (int e = 0; e < 4; e++){ mx[e] = -3.0e38f; sm[e] = 0.f; }

  const char* kgb = (const char*)(kB + bh * (size_t)KLEN * DH);
  const char* vgb = (const char*)(vB + bh * (size_t)KLEN * DH);   // [DH][KLEN]
  const char* rgb = (const char*)(rhB + (size_t)h * KLEN * DH);

  const int jtiles = (i0 >> 6) + 17;

  // ---- prologue: stage prev band -> Rb[1], tile0 K/V/band -> [0] ----
  {
    int tbp = 959 - i0;
    #pragma unroll
    for (int rnd = 0; rnd < 2; rnd++){
      int c = rnd * 256 + tid;
      int row = c >> 3;
      int ch = (c & 7) ^ ((row ^ (row >> 3)) & 7);
      int t = tbp + row; t = t < 0 ? 0 : t;
      stage16(rgb + (size_t)t * 128 + ch * 16, (char*)&Rb[1][0] + c * 16);
    }
    __builtin_amdgcn_sched_barrier(0);
    #pragma unroll
    for (int rnd = 0; rnd < 2; rnd++){
      int c = rnd * 256 + tid;
      int row = c >> 3;
      int ch = (c & 7) ^ ((row ^ (row >> 3)) & 7);
      stage16(kgb + (size_t)row * 128 + ch * 16, (char*)&Kt[0][0] + c * 16);
      stage16(vgb + (size_t)row * 4096 + ch * 16, (char*)&Vt[0][0] + c * 16);
      int t = 1023 - i0 + row;
      stage16(rgb + (size_t)t * 128 + ch * 16, (char*)&Rb[0][0] + c * 16);
    }
    __builtin_amdgcn_sched_barrier(0);
    asm volatile("s_waitcnt vmcnt(6)" ::: "memory");
    __builtin_amdgcn_s_barrier();
    // BD^T for prev band -> Pbd[1]
    #pragma unroll
    for (int n2 = 0; n2 < 4; n2++){
      bf16x8 a0 = *(const bf16x8*)((const char*)&Rb[1][0] + swz(n2 * 16 + lc, lr * 16));
      bf16x8 a1 = *(const bf16x8*)((const char*)&Rb[1][0] + swz(n2 * 16 + lc, 64 + lr * 16));
      f32x4 z = (f32x4){0.f, 0.f, 0.f, 0.f};
      z = MFMA16(a0, qr_[0], z);
      z = MFMA16(a1, qr_[1], z);
      int row = w * 16 + lc;
      uint2 pr; pr.x = pk2(z[0], z[1]); pr.y = pk2(z[2], z[3]);
      *(uint2*)((char*)&Pbd[1][0] + row * 128 + ((n2 * 32 + lr * 8) ^ ((row & 7) << 4))) = pr;
    }
  }

  for (int jt = 0; jt < jtiles; jt++){
    const int j0 = jt * 64;
    const int cur = jt & 1, nxt = cur ^ 1;

    // issue next-tile stages (6; stay in flight across the barrier)
    {
      int jn = (jt + 1 < jtiles) ? j0 + 64 : j0;
      int tb = 1023 - i0 + jn;
      #pragma unroll
      for (int rnd = 0; rnd < 2; rnd++){
        int c = rnd * 256 + tid;
        int row = c >> 3;
        int ch = (c & 7) ^ ((row ^ (row >> 3)) & 7);
        stage16(kgb + (size_t)(jn + row) * 128 + ch * 16, (char*)&Kt[nxt][0] + c * 16);
        stage16(vgb + (size_t)row * 4096 + jn * 2 + ch * 16, (char*)&Vt[nxt][0] + c * 16);
        int t = tb + row; t = t > 2047 ? 2047 : t;
        stage16(rgb + (size_t)t * 128 + ch * 16, (char*)&Rb[nxt][0] + c * 16);
      }
    }
    __builtin_amdgcn_sched_barrier(0);
    asm volatile("s_waitcnt vmcnt(6)" ::: "memory");
    __builtin_amdgcn_s_barrier();

    // AC = (q + r_w_bias) K^T
    f32x4 s[4];
    __builtin_amdgcn_s_setprio(1);
    #pragma unroll
    for (int n = 0; n < 4; n++){
      bf16x8 k0f = *(const bf16x8*)((const char*)&Kt[cur][0] + swz(n * 16 + lc, lr * 16));
      bf16x8 k1f = *(const bf16x8*)((const char*)&Kt[cur][0] + swz(n * 16 + lc, 64 + lr * 16));
      f32x4 z = (f32x4){0.f, 0.f, 0.f, 0.f};
      z = MFMA16(qw_[0], k0f, z);
      z = MFMA16(qw_[1], k1f, z);
      s[n] = z;
    }
    // BD^T for current band -> Pbd[cur] (packed b64 stores)
    #pragma unroll
    for (int n2 = 0; n2 < 4; n2++){
      bf16x8 a0 = *(const bf16x8*)((const char*)&Rb[cur][0] + swz(n2 * 16 + lc, lr * 16));
      bf16x8 a1 = *(const bf16x8*)((const char*)&Rb[cur][0] + swz(n2 * 16 + lc, 64 + lr * 16));
      f32x4 z = (f32x4){0.f, 0.f, 0.f, 0.f};
      z = MFMA16(a0, qr_[0], z);
      z = MFMA16(a1, qr_[1], z);
      int row = w * 16 + lc;
      uint2 pr; pr.x = pk2(z[0], z[1]); pr.y = pk2(z[2], z[3]);
      *(uint2*)((char*)&Pbd[cur][0] + row * 128 + ((n2 * 32 + lr * 8) ^ ((row & 7) << 4))) = pr;
    }
    __builtin_amdgcn_s_setprio(0);
    asm volatile("s_waitcnt lgkmcnt(0)" ::: "memory");
    __builtin_amdgcn_sched_barrier(0);

    // sheared BD pickup + online softmax (DPP 16-lane reductions)
    const char* pbC = (const char*)&Pbd[cur][0];
    const char* pbP = (const char*)&Pbd[nxt][0];
    const bool maskT = (jt == jtiles - 1);
    float nm[4];
    #pragma unroll
    for (int e = 0; e < 4; e++){
      int il = w * 16 + lr * 4 + e;
      float tm = -3.0e38f;
      #pragma unroll
      for (int n = 0; n < 4; n++){
        int dd = n * 16 + lc - (lr * 4 + e) - w * 16;   // jl - il in [-63,63]
        u16 bd = *(const u16*)((dd < 0 ? pbP : pbC) + il * 128 +
                               ((2 * (dd & 63)) ^ ((il & 7) << 4)));
        float x = (s[n][e] + b2f(bd)) * 0.125f;
        if (maskT && dd > 0) x = -1.0e30f;              // j > i + MLEN
        s[n][e] = x;
        tm = fmaxf(tm, x);
      }
      tm = dppmax<0x121>(tm); tm = dppmax<0x122>(tm);
      tm = dppmax<0x124>(tm); tm = dppmax<0x128>(tm);
      nm[e] = fmaxf(mx[e], tm);
    }
    bool need = (nm[0] > mx[0]) | (nm[1] > mx[1]) | (nm[2] > mx[2]) | (nm[3] > mx[3]);
    if (__any(need)){
      #pragma unroll
      for (int e = 0; e < 4; e++){
        float fc = __expf(mx[e] - nm[e]);
        mx[e] = nm[e];
        sm[e] *= fc;
        #pragma unroll
        for (int df = 0; df < 4; df++) O[df][e] *= fc;
      }
    }
    #pragma unroll
    for (int e = 0; e < 4; e++){
      float ps = 0.f;
      #pragma unroll
      for (int n = 0; n < 4; n++){
        float pv = __expf(s[n][e] - mx[e]);
        s[n][e] = pv;
        ps += pv;
      }
      ps = dppadd<0x121>(ps); ps = dppadd<0x122>(ps);
      ps = dppadd<0x124>(ps); ps = dppadd<0x128>(ps);
      sm[e] += ps;
    }
    // P -> LDS (bf16)
    #pragma unroll
    for (int n = 0; n < 4; n++)
      #pragma unroll
      for (int e = 0; e < 4; e++)
        *(u16*)((char*)&Pt[w][0] + swz(lr * 4 + e, (n * 16 + lc) * 2)) = f2bn(s[n][e]);
    asm volatile("s_waitcnt lgkmcnt(0)" ::: "memory");
    __builtin_amdgcn_sched_barrier(0);

    // O += P @ V
    bf16x8 pa0 = *(const bf16x8*)((const char*)&Pt[w][0] + swz(lc, lr * 16));
    bf16x8 pa1 = *(const bf16x8*)((const char*)&Pt[w][0] + swz(lc, 64 + lr * 16));
    __builtin_amdgcn_s_setprio(1);
    #pragma unroll
    for (int df = 0; df < 4; df++){
      bf16x8 v0 = *(const bf16x8*)((const char*)&Vt[cur][0] + swz(df * 16 + lc, lr * 16));
      bf16x8 v1 = *(const bf16x8*)((const char*)&Vt[cur][0] + swz(df * 16 + lc, 64 + lr * 16));
      O[df] = MFMA16(pa0, v0, O[df]);
      O[df] = MFMA16(pa1, v1, O[df]);
    }
    __builtin_amdgcn_s_setprio(0);
    // all reads of [cur] done before next iteration stages into it
    __builtin_amdgcn_s_barrier();
  }

  asm volatile("s_waitcnt vmcnt(0)" ::: "memory");

  #pragma unroll
  for (int e = 0; e < 4; e++){
    float is = 1.0f / sm[e];
    #pragma unroll
    for (int df = 0; df < 4; df++){
      int i = i0 + w * 16 + lr * 4 + e;
      av[(size_t)(i * BSZ + b) * DM + h * DH + df * 16 + lc] = f2bn(O[df][e] * is);
    }
  }
}

// ---------------- residual + LayerNorm ----------------

__global__ __launch_bounds__(256) void ln_k(const float* __restrict__ w,
                                            const float* __restrict__ ao,
                                            const float* __restrict__ gam,
                                            const float* __restrict__ bet,
                                            float* __restrict__ out){
  __shared__ float red[8];
  const int rw = blockIdx.x, t = threadIdx.x, lane = t & 63, wv = t >> 6;
  const float* wr_ = w + (size_t)rw * DM;
  const float* ar_ = ao + (size_t)rw * DM;
  float x[4];
  float s = 0.f, ss = 0.f;
  #pragma unroll
  for (int k2 = 0; k2 < 4; k2++){
    int c = t + k2 * 256;
    float xv = wr_[c] + ar_[c];
    x[k2] = xv; s += xv; ss += xv * xv;
  }
  #pragma unroll
  for (int m2 = 1; m2 < 64; m2 <<= 1){ s += __shfl_xor(s, m2); ss += __shfl_xor(ss, m2); }
  if (lane == 0){ red[wv] = s; red[4 + wv] = ss; }
  __syncthreads();
  s  = red[0] + red[1] + red[2] + red[3];
  ss = red[4] + red[5] + red[6] + red[7];
  float mu = s * (1.f / DM);
  float var = ss * (1.f / DM) - mu * mu;
  float rs = rsqrtf(var + 1e-5f);
  #pragma unroll
  for (int k2 = 0; k2 < 4; k2++){
    int c = t + k2 * 256;
    out[(size_t)rw * DM + c] = (x[k2] - mu) * rs * gam[c] + bet[c];
  }
}

// ---------------- launch ----------------

extern "C" void kernel_launch(void* const* d_in, const int* in_sizes, int n_in,
                              void* d_out, int out_size, void* d_ws, size_t ws_size,
                              hipStream_t stream)
{
  (void)in_sizes; (void)n_in; (void)out_size; (void)ws_size;
  const float* w    = (const float*)d_in[0];
  const float* r    = (const float*)d_in[1];
  const float* mems = (const float*)d_in[2];
  const float* Wqkv = (const float*)d_in[3];
  const float* Wr   = (const float*)d_in[4];
  const float* Wo   = (const float*)d_in[5];
  const float* rwb  = (const float*)d_in[6];
  const float* rrb  = (const float*)d_in[7];
  const float* gam  = (const float*)d_in[8];
  const float* bet  = (const float*)d_in[9];
  float* out = (float*)d_out;

  char* ws = (char*)d_ws;
  size_t off = 0;
  auto alloc = [&](size_t n){ char* p = ws + off; off += (n + 255) & ~(size_t)255; return p; };
  u16* catB  = (u16*)alloc((size_t)KLEN * BSZ * DM * 2);
  u16* rB    = (u16*)alloc((size_t)KLEN * DM * 2);
  u16* WqkvT = (u16*)alloc((size_t)3 * DM * DM * 2);
  u16* WrT   = (u16*)alloc((size_t)DM * DM * 2);
  u16* WoT   = (u16*)alloc((size_t)DM * DM * 2);
  u16* qBuf  = (u16*)alloc((size_t)BSZ * NH * QLEN * DH * 2);
  u16* kBp   = (u16*)alloc((size_t)BSZ * NH * KLEN * DH * 2);
  u16* vBp   = (u16*)alloc((size_t)BSZ * NH * KLEN * DH * 2);   // d-major
  u16* rhB   = (u16*)alloc((size_t)NH * KLEN * DH * 2);
  u16* av    = (u16*)alloc((size_t)QLEN * BSZ * DM * 2);
  float* ao  = (float*)alloc((size_t)QLEN * BSZ * DM * 4);

  conv_cat<<<dim3(8192), 256, 0, stream>>>(mems, w, catB);
  conv_r<<<dim3(2048), 256, 0, stream>>>(r, rB);
  transpose_conv<<<dim3(96, 32), 256, 0, stream>>>(Wqkv, WqkvT, DM, 3 * DM);
  transpose_conv<<<dim3(32, 32), 256, 0, stream>>>(Wr, WrT, DM, DM);
  transpose_conv<<<dim3(32, 32), 256, 0, stream>>>(Wo, WoT, DM, DM);

  // QKV projection: [8192,1024] x [1024,3072]
  gemm_k<0><<<dim3(24, 64), 256, 0, stream>>>(catB, WqkvT, DM, qBuf, kBp, vBp);
  // R projection: [2048,1024] x [1024,1024]
  gemm_k<1><<<dim3(8, 16), 256, 0, stream>>>(rB, WrT, DM, rhB, nullptr, nullptr);

  // fused attention: 1024 blocks x 256 threads (2 blocks/CU, 72 KB LDS each)
  attn_k<<<dim3(1024), 256, 0, stream>>>(qBuf, kBp, vBp, rhB, rwb, rrb, av);

  // output projection: [4096,1024] x [1024,1024]
  gemm_k<3><<<dim3(8, 32), 256, 0, stream>>>(av, WoT, DM, ao, nullptr, nullptr);
  ln_k<<<dim3(4096), 256, 0, stream>>>(w, ao, gam, bet, out);
}

// Round 8
// 299.200 us; speedup vs baseline: 1.9442x; 1.0347x over previous
//
#include <hip/hip_runtime.h>
#include <hip/hip_bf16.h>
#include <stdint.h>

#define QLEN 1024
#define MLEN 1024
#define KLEN 2048
#define BSZ 4
#define NH 16
#define DH 64
#define DM 1024

typedef __attribute__((ext_vector_type(8))) short bf16x8;
typedef __attribute__((ext_vector_type(4))) float f32x4;
typedef unsigned short u16;
typedef unsigned int u32;

typedef unsigned int __attribute__((address_space(1))) gu32;
typedef unsigned int __attribute__((address_space(3))) lu32;

__device__ __forceinline__ void stage16(const void* g, void* l){
  __builtin_amdgcn_global_load_lds((const gu32*)g, (lu32*)l, 16, 0, 0);
}

__device__ __forceinline__ u16 f2b(float f){
  u32 u = __builtin_bit_cast(u32, f);
  u32 r = (u + 0x7FFFu + ((u >> 16) & 1u)) >> 16;
  return (u16)r;
}
__device__ __forceinline__ float b2f(u16 v){
  u32 u = ((u32)v) << 16;
  return __builtin_bit_cast(float, u);
}
// native converts (compiler emits v_cvt_pk_bf16_f32); bits via memcpy since
// __hip_bfloat16 types are not trivially copyable (no bit_cast).
__device__ __forceinline__ u16 f2bn(float f){
  __hip_bfloat16 h = __float2bfloat16(f);
  u16 r; __builtin_memcpy(&r, &h, 2); return r;
}
__device__ __forceinline__ u32 pk2(float a, float b){
  float2 t; t.x = a; t.y = b;
  __hip_bfloat162 h = __float22bfloat162_rn(t);
  u32 r; __builtin_memcpy(&r, &h, 4); return r;
}

// XOR swizzle for [rows][64]bf16 tiles (128B rows)
__device__ __forceinline__ int swz(int row, int byteoff){
  return (row << 7) + (byteoff ^ (((row ^ (row >> 3)) & 7) << 4));
}

// DPP 16-lane-row reductions (row_ror:N = 0x120+N)
template<int C>
__device__ __forceinline__ float dppmax(float x){
  int t = __builtin_amdgcn_update_dpp(0, __builtin_bit_cast(int, x), C, 0xf, 0xf, true);
  return fmaxf(x, __builtin_bit_cast(float, t));
}
template<int C>
__device__ __forceinline__ float dppadd(float x){
  int t = __builtin_amdgcn_update_dpp(0, __builtin_bit_cast(int, x), C, 0xf, 0xf, true);
  return x + __builtin_bit_cast(float, t);
}

#define MFMA16(a, b, c) __builtin_amdgcn_mfma_f32_16x16x32_bf16(a, b, c, 0, 0, 0)

// ---------------- conversion kernels ----------------

__global__ __launch_bounds__(256) void conv_cat(const float* __restrict__ mems,
                                                const float* __restrict__ w,
                                                u16* __restrict__ dst){
  int idx = blockIdx.x * 256 + threadIdx.x;
  const int memf4 = MLEN * BSZ * DM / 4;
  float4 v = (idx < memf4) ? ((const float4*)mems)[idx]
                           : ((const float4*)w)[idx - memf4];
  ushort4 o;
  o.x = f2b(v.x); o.y = f2b(v.y); o.z = f2b(v.z); o.w = f2b(v.w);
  ((ushort4*)dst)[idx] = o;
}

__global__ __launch_bounds__(256) void conv_r(const float* __restrict__ r,
                                              u16* __restrict__ dst){
  int idx = blockIdx.x * 256 + threadIdx.x;
  float4 v = ((const float4*)r)[idx];
  ushort4 o;
  o.x = f2b(v.x); o.y = f2b(v.y); o.z = f2b(v.z); o.w = f2b(v.w);
  ((ushort4*)dst)[idx] = o;
}

__global__ __launch_bounds__(256) void transpose_conv(const float* __restrict__ src,
                                                      u16* __restrict__ dst,
                                                      int R, int C){
  __shared__ float tile[32][33];
  int c0 = blockIdx.x * 32, r0 = blockIdx.y * 32;
  int tx = threadIdx.x & 31, ty = threadIdx.x >> 5;
  #pragma unroll
  for (int rr = ty; rr < 32; rr += 8)
    tile[rr][tx] = src[(size_t)(r0 + rr) * C + c0 + tx];
  __syncthreads();
  #pragma unroll
  for (int rr = ty; rr < 32; rr += 8)
    dst[(size_t)(c0 + rr) * R + r0 + tx] = f2b(tile[tx][rr]);
}

// ---------------- bf16 MFMA GEMM (128x128 tile, BK=32, 2-phase pipeline) ----
// LDS double-buffer; stage tile k+1 before computing tile k; counted vmcnt(4);
// raw barriers (no vmem drain). MODE 0: QKV epilogue (q raw; k; v d-major).
// MODE 1: R projection epilogue. MODE 3: plain f32 row-major C.

template<int MODE>
__global__ __launch_bounds__(256, 4) void gemm_k(
    const u16* __restrict__ A, const u16* __restrict__ Bt, int K,
    void* __restrict__ o0, void* __restrict__ o1, void* __restrict__ o2)
{
  __shared__ u16 As[2][128 * 32];
  __shared__ u16 Bs[2][128 * 32];
  const int tid = threadIdx.x;
  const int lane = tid & 63, w = tid >> 6;
  const int wr = w >> 1, wc = w & 1;
  const int lr = lane >> 4, lc = lane & 15;
  const int m0 = blockIdx.y * 128, n0 = blockIdx.x * 128;

  f32x4 acc[4][4];
  #pragma unroll
  for (int i = 0; i < 4; i++)
    #pragma unroll
    for (int j = 0; j < 4; j++)
      acc[i][j] = (f32x4){0.f, 0.f, 0.f, 0.f};

  // prologue: stage tile 0 into buffer 0 (4 loads in flight)
  #pragma unroll
  for (int rnd = 0; rnd < 2; rnd++){
    int c = rnd * 256 + tid;
    int row = c >> 2, kc = c & 3;
    stage16((const char*)A + ((size_t)(m0 + row) * K + kc * 8) * 2,
            (char*)As + c * 16);
    stage16((const char*)Bt + ((size_t)(n0 + row) * K + kc * 8) * 2,
            (char*)Bs + c * 16);
  }

  const int NK = K >> 5;
  for (int it = 0; it < NK; ++it){
    const int cur = it & 1, nxt = cur ^ 1;
    if (it + 1 < NK){
      const int k0 = (it + 1) << 5;
      #pragma unroll
      for (int rnd = 0; rnd < 2; rnd++){
        int c = rnd * 256 + tid;
        int row = c >> 2, kc = c & 3;
        stage16((const char*)A + ((size_t)(m0 + row) * K + k0 + kc * 8) * 2,
                (char*)As + nxt * 8192 + c * 16);
        stage16((const char*)Bt + ((size_t)(n0 + row) * K + k0 + kc * 8) * 2,
                (char*)Bs + nxt * 8192 + c * 16);
      }
      asm volatile("s_waitcnt vmcnt(4)" ::: "memory");
    } else {
      asm volatile("s_waitcnt vmcnt(0)" ::: "memory");
    }
    __builtin_amdgcn_s_barrier();

    bf16x8 af[4], bfr[4];
    #pragma unroll
    for (int mf = 0; mf < 4; mf++)
      af[mf] = *(const bf16x8*)((const char*)As + cur * 8192 +
                                (wr * 64 + mf * 16 + lc) * 64 + lr * 16);
    #pragma unroll
    for (int nf = 0; nf < 4; nf++)
      bfr[nf] = *(const bf16x8*)((const char*)Bs + cur * 8192 +
                                 (wc * 64 + nf * 16 + lc) * 64 + lr * 16);
    #pragma unroll
    for (int mf = 0; mf < 4; mf++)
      #pragma unroll
      for (int nf = 0; nf < 4; nf++)
        acc[mf][nf] = MFMA16(af[mf], bfr[nf], acc[mf][nf]);
    __builtin_amdgcn_s_barrier();   // reads of [cur] done before restage
  }

  #pragma unroll
  for (int mf = 0; mf < 4; mf++){
    #pragma unroll
    for (int nf = 0; nf < 4; nf++){
      #pragma unroll
      for (int e = 0; e < 4; e++){
        float v = acc[mf][nf][e];
        int row = m0 + wr * 64 + mf * 16 + lr * 4 + e;
        int col = n0 + wc * 64 + nf * 16 + lc;
        if constexpr (MODE == 0){
          int t = row >> 2, bb = row & 3;
          int s = col >> 10, rem = col & 1023;
          int h = rem >> 6, d = rem & 63;
          if (s == 0){
            if (t >= MLEN)
              ((u16*)o0)[((size_t)(bb * NH + h) * QLEN + (t - MLEN)) * DH + d] = f2b(v);
          } else if (s == 1){
            ((u16*)o1)[((size_t)(bb * NH + h) * KLEN + t) * DH + d] = f2b(v);    // k [bh][t][d]
          } else {
            ((u16*)o2)[((size_t)(bb * NH + h) * DH + d) * KLEN + t] = f2b(v);    // v [bh][d][t]
          }
        } else if constexpr (MODE == 1){
          int h = col >> 6, d = col & 63;
          ((u16*)o0)[((size_t)h * KLEN + row) * DH + d] = f2b(v);
        } else {
          ((float*)o0)[(size_t)row * DM + col] = v;
        }
      }
    }
  }
}

// ---------------- fused flash attention, 64-row blocks, 4 waves ----------------
// r7 structure (block-shared K/V/rh staging, swapped-BD Pbd, counted vmcnt(6))
// + exp2-domain softmax (0.125*log2e folded into q fragments), defer-max THR=8,
// hoisted jt-invariant pickup offsets.

__global__ __launch_bounds__(256, 2) void attn_k(
    const u16* __restrict__ qB,  const u16* __restrict__ kB,
    const u16* __restrict__ vB,  const u16* __restrict__ rhB,
    const float* __restrict__ rwb, const float* __restrict__ rrb,
    u16* __restrict__ av)
{
  __shared__ u16 Kt[2][64 * 64];      // [j][d] swizzled     16 KB
  __shared__ u16 Vt[2][64 * 64];      // [d][j] swizzled     16 KB
  __shared__ u16 Rb[2][64 * 64];      // band [t'][d] swz    16 KB
  __shared__ u16 Pt[4][16 * 64];      // per-wave P [r][j]    8 KB
  __shared__ u16 Pbd[2][64 * 64];     // BD [r][t'] row-XOR  16 KB   total 72 KB

  const int tid = threadIdx.x, lane = tid & 63, w = tid >> 6;
  const int lr = lane >> 4, lc = lane & 15;

  // r3-validated XCD remap: bid%8 = XCD, i fastest within an XCD's chunk
  const int bid = blockIdx.x;
  const int nid = (bid & 7) * 128 + (bid >> 3);
  const int i0 = (nid & 15) * 64;
  const int h  = (nid >> 4) & 15;
  const int b  = nid >> 8;
  const size_t bh = (size_t)b * NH + h;

  const float SCL = 0.18033688011112042f;   // 0.125 * log2(e) -> exp2 domain

  // Q fragments with biases, pre-scaled (rows i0 + w*16 + lc)
  bf16x8 qw_[2], qr_[2];
  #pragma unroll
  for (int ks = 0; ks < 2; ks++){
    bf16x8 qv = *(const bf16x8*)(qB + (bh * QLEN + i0 + w * 16 + lc) * DH + ks * 32 + lr * 8);
    #pragma unroll
    for (int e2 = 0; e2 < 8; e2++){
      int d = ks * 32 + lr * 8 + e2;
      float q32 = b2f((u16)qv[e2]);
      qw_[ks][e2] = (short)f2bn((q32 + rwb[h * DH + d]) * SCL);
      qr_[ks][e2] = (short)f2bn((q32 + rrb[h * DH + d]) * SCL);
    }
  }

  // jt-invariant sheared-pickup metadata
  int pbo[4][4]; bool sel[4][4], mskc[4][4];
  #pragma unroll
  for (int n = 0; n < 4; n++)
    #pragma unroll
    for (int e = 0; e < 4; e++){
      int il = w * 16 + lr * 4 + e;
      int dd = n * 16 + lc - il;
      pbo[n][e] = il * 128 + ((2 * (dd & 63)) ^ ((il & 7) << 4));
      sel[n][e] = dd < 0;
      mskc[n][e] = dd > 0;
    }

  f32x4 O[4];
  float mx[4], sm[4];
  #pragma unroll
  for (int df = 0; df < 4; df++) O[df] = (f32x4){0.f, 0.f, 0.f, 0.f};
  #pragma unroll
  for (int e = 0; e < 4; e++){ mx[e] = -3.0e38f; sm[e] = 0.f; }

  const char* kgb = (const char*)(kB + bh * (size_t)KLEN * DH);
  const char* vgb = (const char*)(vB + bh * (size_t)KLEN * DH);   // [DH][KLEN]
  const char* rgb = (const char*)(rhB + (size_t)h * KLEN * DH);

  const int jtiles = (i0 >> 6) + 17;

  // ---- prologue: stage prev band -> Rb[1], tile0 K/V/band -> [0] ----
  {
    int tbp = 959 - i0;
    #pragma unroll
    for (int rnd = 0; rnd < 2; rnd++){
      int c = rnd * 256 + tid;
      int row = c >> 3;
      int ch = (c & 7) ^ ((row ^ (row >> 3)) & 7);
      int t = tbp + row; t = t < 0 ? 0 : t;
      stage16(rgb + (size_t)t * 128 + ch * 16, (char*)&Rb[1][0] + c * 16);
    }
    __builtin_amdgcn_sched_barrier(0);
    #pragma unroll
    for (int rnd = 0; rnd < 2; rnd++){
      int c = rnd * 256 + tid;
      int row = c >> 3;
      int ch = (c & 7) ^ ((row ^ (row >> 3)) & 7);
      stage16(kgb + (size_t)row * 128 + ch * 16, (char*)&Kt[0][0] + c * 16);
      stage16(vgb + (size_t)row * 4096 + ch * 16, (char*)&Vt[0][0] + c * 16);
      int t = 1023 - i0 + row;
      stage16(rgb + (size_t)t * 128 + ch * 16, (char*)&Rb[0][0] + c * 16);
    }
    __builtin_amdgcn_sched_barrier(0);
    asm volatile("s_waitcnt vmcnt(6)" ::: "memory");
    __builtin_amdgcn_s_barrier();
    // BD^T for prev band -> Pbd[1]
    #pragma unroll
    for (int n2 = 0; n2 < 4; n2++){
      bf16x8 a0 = *(const bf16x8*)((const char*)&Rb[1][0] + swz(n2 * 16 + lc, lr * 16));
      bf16x8 a1 = *(const bf16x8*)((const char*)&Rb[1][0] + swz(n2 * 16 + lc, 64 + lr * 16));
      f32x4 z = (f32x4){0.f, 0.f, 0.f, 0.f};
      z = MFMA16(a0, qr_[0], z);
      z = MFMA16(a1, qr_[1], z);
      int row = w * 16 + lc;
      uint2 pr; pr.x = pk2(z[0], z[1]); pr.y = pk2(z[2], z[3]);
      *(uint2*)((char*)&Pbd[1][0] + row * 128 + ((n2 * 32 + lr * 8) ^ ((row & 7) << 4))) = pr;
    }
  }

  for (int jt = 0; jt < jtiles; jt++){
    const int j0 = jt * 64;
    const int cur = jt & 1, nxt = cur ^ 1;

    // issue next-tile stages (6; stay in flight across the barrier)
    {
      int jn = (jt + 1 < jtiles) ? j0 + 64 : j0;
      int tb = 1023 - i0 + jn;
      #pragma unroll
      for (int rnd = 0; rnd < 2; rnd++){
        int c = rnd * 256 + tid;
        int row = c >> 3;
        int ch = (c & 7) ^ ((row ^ (row >> 3)) & 7);
        stage16(kgb + (size_t)(jn + row) * 128 + ch * 16, (char*)&Kt[nxt][0] + c * 16);
        stage16(vgb + (size_t)row * 4096 + jn * 2 + ch * 16, (char*)&Vt[nxt][0] + c * 16);
        int t = tb + row; t = t > 2047 ? 2047 : t;
        stage16(rgb + (size_t)t * 128 + ch * 16, (char*)&Rb[nxt][0] + c * 16);
      }
    }
    __builtin_amdgcn_sched_barrier(0);
    asm volatile("s_waitcnt vmcnt(6)" ::: "memory");
    __builtin_amdgcn_s_barrier();

    // AC = scaled (q + r_w_bias) K^T
    f32x4 s[4];
    __builtin_amdgcn_s_setprio(1);
    #pragma unroll
    for (int n = 0; n < 4; n++){
      bf16x8 k0f = *(const bf16x8*)((const char*)&Kt[cur][0] + swz(n * 16 + lc, lr * 16));
      bf16x8 k1f = *(const bf16x8*)((const char*)&Kt[cur][0] + swz(n * 16 + lc, 64 + lr * 16));
      f32x4 z = (f32x4){0.f, 0.f, 0.f, 0.f};
      z = MFMA16(qw_[0], k0f, z);
      z = MFMA16(qw_[1], k1f, z);
      s[n] = z;
    }
    // BD^T for current band -> Pbd[cur] (packed b64 stores)
    #pragma unroll
    for (int n2 = 0; n2 < 4; n2++){
      bf16x8 a0 = *(const bf16x8*)((const char*)&Rb[cur][0] + swz(n2 * 16 + lc, lr * 16));
      bf16x8 a1 = *(const bf16x8*)((const char*)&Rb[cur][0] + swz(n2 * 16 + lc, 64 + lr * 16));
      f32x4 z = (f32x4){0.f, 0.f, 0.f, 0.f};
      z = MFMA16(a0, qr_[0], z);
      z = MFMA16(a1, qr_[1], z);
      int row = w * 16 + lc;
      uint2 pr; pr.x = pk2(z[0], z[1]); pr.y = pk2(z[2], z[3]);
      *(uint2*)((char*)&Pbd[cur][0] + row * 128 + ((n2 * 32 + lr * 8) ^ ((row & 7) << 4))) = pr;
    }
    __builtin_amdgcn_s_setprio(0);
    asm volatile("s_waitcnt lgkmcnt(0)" ::: "memory");
    __builtin_amdgcn_sched_barrier(0);

    // sheared BD pickup + online softmax (exp2 domain, defer-max THR=8)
    const char* pbC = (const char*)&Pbd[cur][0];
    const char* pbP = (const char*)&Pbd[nxt][0];
    const bool maskT = (jt == jtiles - 1);
    float tmv[4];
    #pragma unroll
    for (int e = 0; e < 4; e++){
      float tm = -3.0e38f;
      #pragma unroll
      for (int n = 0; n < 4; n++){
        u16 bd = *(const u16*)((sel[n][e] ? pbP : pbC) + pbo[n][e]);
        float x = s[n][e] + b2f(bd);
        if (maskT && mskc[n][e]) x = -1.0e30f;    // j > i + MLEN
        s[n][e] = x;
        tm = fmaxf(tm, x);
      }
      tm = dppmax<0x121>(tm); tm = dppmax<0x122>(tm);
      tm = dppmax<0x124>(tm); tm = dppmax<0x128>(tm);
      tmv[e] = tm;
    }
    bool need = false;
    float nm[4];
    #pragma unroll
    for (int e = 0; e < 4; e++){
      nm[e] = fmaxf(mx[e], tmv[e]);
      need = need | (tmv[e] > mx[e] + 8.0f);
    }
    if (__any(need)){
      #pragma unroll
      for (int e = 0; e < 4; e++){
        float fc = __builtin_amdgcn_exp2f(mx[e] - nm[e]);
        mx[e] = nm[e];
        sm[e] *= fc;
        #pragma unroll
        for (int df = 0; df < 4; df++) O[df][e] *= fc;
      }
    }
    #pragma unroll
    for (int e = 0; e < 4; e++){
      float ps = 0.f;
      #pragma unroll
      for (int n = 0; n < 4; n++){
        float pv = __builtin_amdgcn_exp2f(s[n][e] - mx[e]);   // <= 2^8
        s[n][e] = pv;
        ps += pv;
      }
      ps = dppadd<0x121>(ps); ps = dppadd<0x122>(ps);
      ps = dppadd<0x124>(ps); ps = dppadd<0x128>(ps);
      sm[e] += ps;
    }
    // P -> LDS (bf16)
    #pragma unroll
    for (int n = 0; n < 4; n++)
      #pragma unroll
      for (int e = 0; e < 4; e++)
        *(u16*)((char*)&Pt[w][0] + swz(lr * 4 + e, (n * 16 + lc) * 2)) = f2bn(s[n][e]);
    asm volatile("s_waitcnt lgkmcnt(0)" ::: "memory");
    __builtin_amdgcn_sched_barrier(0);

    // O += P @ V
    bf16x8 pa0 = *(const bf16x8*)((const char*)&Pt[w][0] + swz(lc, lr * 16));
    bf16x8 pa1 = *(const bf16x8*)((const char*)&Pt[w][0] + swz(lc, 64 + lr * 16));
    __builtin_amdgcn_s_setprio(1);
    #pragma unroll
    for (int df = 0; df < 4; df++){
      bf16x8 v0 = *(const bf16x8*)((const char*)&Vt[cur][0] + swz(df * 16 + lc, lr * 16));
      bf16x8 v1 = *(const bf16x8*)((const char*)&Vt[cur][0] + swz(df * 16 + lc, 64 + lr * 16));
      O[df] = MFMA16(pa0, v0, O[df]);
      O[df] = MFMA16(pa1, v1, O[df]);
    }
    __builtin_amdgcn_s_setprio(0);
    // all reads of [cur] done before next iteration stages into it
    __builtin_amdgcn_s_barrier();
  }

  asm volatile("s_waitcnt vmcnt(0)" ::: "memory");

  #pragma unroll
  for (int e = 0; e < 4; e++){
    float is = 1.0f / sm[e];
    #pragma unroll
    for (int df = 0; df < 4; df++){
      int i = i0 + w * 16 + lr * 4 + e;
      av[(size_t)(i * BSZ + b) * DM + h * DH + df * 16 + lc] = f2bn(O[df][e] * is);
    }
  }
}

// ---------------- residual + LayerNorm ----------------

__global__ __launch_bounds__(256) void ln_k(const float* __restrict__ w,
                                            const float* __restrict__ ao,
                                            const float* __restrict__ gam,
                                            const float* __restrict__ bet,
                                            float* __restrict__ out){
  __shared__ float red[8];
  const int rw = blockIdx.x, t = threadIdx.x, lane = t & 63, wv = t >> 6;
  const float* wr_ = w + (size_t)rw * DM;
  const float* ar_ = ao + (size_t)rw * DM;
  float x[4];
  float s = 0.f, ss = 0.f;
  #pragma unroll
  for (int k2 = 0; k2 < 4; k2++){
    int c = t + k2 * 256;
    float xv = wr_[c] + ar_[c];
    x[k2] = xv; s += xv; ss += xv * xv;
  }
  #pragma unroll
  for (int m2 = 1; m2 < 64; m2 <<= 1){ s += __shfl_xor(s, m2); ss += __shfl_xor(ss, m2); }
  if (lane == 0){ red[wv] = s; red[4 + wv] = ss; }
  __syncthreads();
  s  = red[0] + red[1] + red[2] + red[3];
  ss = red[4] + red[5] + red[6] + red[7];
  float mu = s * (1.f / DM);
  float var = ss * (1.f / DM) - mu * mu;
  float rs = rsqrtf(var + 1e-5f);
  #pragma unroll
  for (int k2 = 0; k2 < 4; k2++){
    int c = t + k2 * 256;
    out[(size_t)rw * DM + c] = (x[k2] - mu) * rs * gam[c] + bet[c];
  }
}

// ---------------- launch ----------------

extern "C" void kernel_launch(void* const* d_in, const int* in_sizes, int n_in,
                              void* d_out, int out_size, void* d_ws, size_t ws_size,
                              hipStream_t stream)
{
  (void)in_sizes; (void)n_in; (void)out_size; (void)ws_size;
  const float* w    = (const float*)d_in[0];
  const float* r    = (const float*)d_in[1];
  const float* mems = (const float*)d_in[2];
  const float* Wqkv = (const float*)d_in[3];
  const float* Wr   = (const float*)d_in[4];
  const float* Wo   = (const float*)d_in[5];
  const float* rwb  = (const float*)d_in[6];
  const float* rrb  = (const float*)d_in[7];
  const float* gam  = (const float*)d_in[8];
  const float* bet  = (const float*)d_in[9];
  float* out = (float*)d_out;

  char* ws = (char*)d_ws;
  size_t off = 0;
  auto alloc = [&](size_t n){ char* p = ws + off; off += (n + 255) & ~(size_t)255; return p; };
  u16* catB  = (u16*)alloc((size_t)KLEN * BSZ * DM * 2);
  u16* rB    = (u16*)alloc((size_t)KLEN * DM * 2);
  u16* WqkvT = (u16*)alloc((size_t)3 * DM * DM * 2);
  u16* WrT   = (u16*)alloc((size_t)DM * DM * 2);
  u16* WoT   = (u16*)alloc((size_t)DM * DM * 2);
  u16* qBuf  = (u16*)alloc((size_t)BSZ * NH * QLEN * DH * 2);
  u16* kBp   = (u16*)alloc((size_t)BSZ * NH * KLEN * DH * 2);
  u16* vBp   = (u16*)alloc((size_t)BSZ * NH * KLEN * DH * 2);   // d-major
  u16* rhB   = (u16*)alloc((size_t)NH * KLEN * DH * 2);
  u16* av    = (u16*)alloc((size_t)QLEN * BSZ * DM * 2);
  float* ao  = (float*)alloc((size_t)QLEN * BSZ * DM * 4);

  conv_cat<<<dim3(8192), 256, 0, stream>>>(mems, w, catB);
  conv_r<<<dim3(2048), 256, 0, stream>>>(r, rB);
  transpose_conv<<<dim3(96, 32), 256, 0, stream>>>(Wqkv, WqkvT, DM, 3 * DM);
  transpose_conv<<<dim3(32, 32), 256, 0, stream>>>(Wr, WrT, DM, DM);
  transpose_conv<<<dim3(32, 32), 256, 0, stream>>>(Wo, WoT, DM, DM);

  // QKV projection: [8192,1024] x [1024,3072]
  gemm_k<0><<<dim3(24, 64), 256, 0, stream>>>(catB, WqkvT, DM, qBuf, kBp, vBp);
  // R projection: [2048,1024] x [1024,1024]
  gemm_k<1><<<dim3(8, 16), 256, 0, stream>>>(rB, WrT, DM, rhB, nullptr, nullptr);

  // fused attention: 1024 blocks x 256 threads (2 blocks/CU, 72 KB LDS each)
  attn_k<<<dim3(1024), 256, 0, stream>>>(qBuf, kBp, vBp, rhB, rwb, rrb, av);

  // output projection: [4096,1024] x [1024,1024]
  gemm_k<3><<<dim3(8, 32), 256, 0, stream>>>(av, WoT, DM, ao, nullptr, nullptr);
  ln_k<<<dim3(4096), 256, 0, stream>>>(w, ao, gam, bet, out);
}

// Round 9
// 290.714 us; speedup vs baseline: 2.0010x; 1.0292x over previous
//
#include <hip/hip_runtime.h>
#include <hip/hip_bf16.h>
#include <stdint.h>

#define QLEN 1024
#define MLEN 1024
#define KLEN 2048
#define BSZ 4
#define NH 16
#define DH 64
#define DM 1024

typedef __attribute__((ext_vector_type(8))) short bf16x8;
typedef __attribute__((ext_vector_type(4))) float f32x4;
typedef unsigned short u16;
typedef unsigned int u32;

typedef unsigned int __attribute__((address_space(1))) gu32;
typedef unsigned int __attribute__((address_space(3))) lu32;

__device__ __forceinline__ void stage16(const void* g, void* l){
  __builtin_amdgcn_global_load_lds((const gu32*)g, (lu32*)l, 16, 0, 0);
}

__device__ __forceinline__ u16 f2b(float f){
  u32 u = __builtin_bit_cast(u32, f);
  u32 r = (u + 0x7FFFu + ((u >> 16) & 1u)) >> 16;
  return (u16)r;
}
__device__ __forceinline__ float b2f(u16 v){
  u32 u = ((u32)v) << 16;
  return __builtin_bit_cast(float, u);
}
// native converts (compiler emits v_cvt_pk_bf16_f32); bits via memcpy since
// __hip_bfloat16 types are not trivially copyable (no bit_cast).
__device__ __forceinline__ u16 f2bn(float f){
  __hip_bfloat16 h = __float2bfloat16(f);
  u16 r; __builtin_memcpy(&r, &h, 2); return r;
}
__device__ __forceinline__ u32 pk2(float a, float b){
  float2 t; t.x = a; t.y = b;
  __hip_bfloat162 h = __float22bfloat162_rn(t);
  u32 r; __builtin_memcpy(&r, &h, 4); return r;
}

// XOR swizzle for [rows][64]bf16 tiles (128B rows)
__device__ __forceinline__ int swz(int row, int byteoff){
  return (row << 7) + (byteoff ^ (((row ^ (row >> 3)) & 7) << 4));
}

// DPP 16-lane-row reductions (row_ror:N = 0x120+N)
template<int C>
__device__ __forceinline__ float dppmax(float x){
  int t = __builtin_amdgcn_update_dpp(0, __builtin_bit_cast(int, x), C, 0xf, 0xf, true);
  return fmaxf(x, __builtin_bit_cast(float, t));
}

#define MFMA16(a, b, c) __builtin_amdgcn_mfma_f32_16x16x32_bf16(a, b, c, 0, 0, 0)

// ---------------- conversion kernels (merged) ----------------

__global__ __launch_bounds__(256) void conv_all(const float* __restrict__ mems,
                                                const float* __restrict__ w,
                                                const float* __restrict__ r,
                                                u16* __restrict__ catB,
                                                u16* __restrict__ rB){
  int bx = blockIdx.x;
  if (bx < 8192){
    int idx = bx * 256 + threadIdx.x;                 // float4 index
    const int memf4 = MLEN * BSZ * DM / 4;
    float4 v = (idx < memf4) ? ((const float4*)mems)[idx]
                             : ((const float4*)w)[idx - memf4];
    ushort4 o;
    o.x = f2b(v.x); o.y = f2b(v.y); o.z = f2b(v.z); o.w = f2b(v.w);
    ((ushort4*)catB)[idx] = o;
  } else {
    int idx = (bx - 8192) * 256 + threadIdx.x;
    float4 v = ((const float4*)r)[idx];
    ushort4 o;
    o.x = f2b(v.x); o.y = f2b(v.y); o.z = f2b(v.z); o.w = f2b(v.w);
    ((ushort4*)rB)[idx] = o;
  }
}

// transpose+convert all three weights in one launch: src [1024][C] -> dst [C][1024]
__global__ __launch_bounds__(256) void transpose3(const float* __restrict__ s0, u16* __restrict__ d0,
                                                  const float* __restrict__ s1, u16* __restrict__ d1,
                                                  const float* __restrict__ s2, u16* __restrict__ d2){
  __shared__ float tile[32][33];
  int bx = blockIdx.x;
  const float* src; u16* dst; int C, c0;
  if (bx < 96){ src = s0; dst = d0; C = 3 * DM; c0 = bx * 32; }
  else if (bx < 128){ src = s1; dst = d1; C = DM; c0 = (bx - 96) * 32; }
  else { src = s2; dst = d2; C = DM; c0 = (bx - 128) * 32; }
  int r0 = blockIdx.y * 32;
  int tx = threadIdx.x & 31, ty = threadIdx.x >> 5;
  #pragma unroll
  for (int rr = ty; rr < 32; rr += 8)
    tile[rr][tx] = src[(size_t)(r0 + rr) * C + c0 + tx];
  __syncthreads();
  #pragma unroll
  for (int rr = ty; rr < 32; rr += 8)
    dst[(size_t)(c0 + rr) * DM + r0 + tx] = f2b(tile[tx][rr]);
}

// ---------------- bf16 MFMA GEMM (128x128 tile, BK=32, 2-phase pipeline) ----
// LDS double-buffer; stage tile k+1 before computing tile k; counted vmcnt(4);
// raw barriers (no vmem drain). MODE 0: QKV epilogue (q raw; k; v d-major).
// MODE 1: R projection epilogue. MODE 3: plain f32 row-major C.

template<int MODE>
__global__ __launch_bounds__(256, 4) void gemm_k(
    const u16* __restrict__ A, const u16* __restrict__ Bt, int K,
    void* __restrict__ o0, void* __restrict__ o1, void* __restrict__ o2)
{
  __shared__ u16 As[2][128 * 32];
  __shared__ u16 Bs[2][128 * 32];
  const int tid = threadIdx.x;
  const int lane = tid & 63, w = tid >> 6;
  const int wr = w >> 1, wc = w & 1;
  const int lr = lane >> 4, lc = lane & 15;
  const int m0 = blockIdx.y * 128, n0 = blockIdx.x * 128;

  f32x4 acc[4][4];
  #pragma unroll
  for (int i = 0; i < 4; i++)
    #pragma unroll
    for (int j = 0; j < 4; j++)
      acc[i][j] = (f32x4){0.f, 0.f, 0.f, 0.f};

  // prologue: stage tile 0 into buffer 0 (4 loads in flight)
  #pragma unroll
  for (int rnd = 0; rnd < 2; rnd++){
    int c = rnd * 256 + tid;
    int row = c >> 2, kc = c & 3;
    stage16((const char*)A + ((size_t)(m0 + row) * K + kc * 8) * 2,
            (char*)As + c * 16);
    stage16((const char*)Bt + ((size_t)(n0 + row) * K + kc * 8) * 2,
            (char*)Bs + c * 16);
  }

  const int NK = K >> 5;
  for (int it = 0; it < NK; ++it){
    const int cur = it & 1, nxt = cur ^ 1;
    if (it + 1 < NK){
      const int k0 = (it + 1) << 5;
      #pragma unroll
      for (int rnd = 0; rnd < 2; rnd++){
        int c = rnd * 256 + tid;
        int row = c >> 2, kc = c & 3;
        stage16((const char*)A + ((size_t)(m0 + row) * K + k0 + kc * 8) * 2,
                (char*)As + nxt * 8192 + c * 16);
        stage16((const char*)Bt + ((size_t)(n0 + row) * K + k0 + kc * 8) * 2,
                (char*)Bs + nxt * 8192 + c * 16);
      }
      asm volatile("s_waitcnt vmcnt(4)" ::: "memory");
    } else {
      asm volatile("s_waitcnt vmcnt(0)" ::: "memory");
    }
    __builtin_amdgcn_s_barrier();

    bf16x8 af[4], bfr[4];
    #pragma unroll
    for (int mf = 0; mf < 4; mf++)
      af[mf] = *(const bf16x8*)((const char*)As + cur * 8192 +
                                (wr * 64 + mf * 16 + lc) * 64 + lr * 16);
    #pragma unroll
    for (int nf = 0; nf < 4; nf++)
      bfr[nf] = *(const bf16x8*)((const char*)Bs + cur * 8192 +
                                 (wc * 64 + nf * 16 + lc) * 64 + lr * 16);
    #pragma unroll
    for (int mf = 0; mf < 4; mf++)
      #pragma unroll
      for (int nf = 0; nf < 4; nf++)
        acc[mf][nf] = MFMA16(af[mf], bfr[nf], acc[mf][nf]);
    __builtin_amdgcn_s_barrier();   // reads of [cur] done before restage
  }

  #pragma unroll
  for (int mf = 0; mf < 4; mf++){
    #pragma unroll
    for (int nf = 0; nf < 4; nf++){
      #pragma unroll
      for (int e = 0; e < 4; e++){
        float v = acc[mf][nf][e];
        int row = m0 + wr * 64 + mf * 16 + lr * 4 + e;
        int col = n0 + wc * 64 + nf * 16 + lc;
        if constexpr (MODE == 0){
          int t = row >> 2, bb = row & 3;
          int s = col >> 10, rem = col & 1023;
          int h = rem >> 6, d = rem & 63;
          if (s == 0){
            if (t >= MLEN)
              ((u16*)o0)[((size_t)(bb * NH + h) * QLEN + (t - MLEN)) * DH + d] = f2b(v);
          } else if (s == 1){
            ((u16*)o1)[((size_t)(bb * NH + h) * KLEN + t) * DH + d] = f2b(v);    // k [bh][t][d]
          } else {
            ((u16*)o2)[((size_t)(bb * NH + h) * DH + d) * KLEN + t] = f2b(v);    // v [bh][d][t]
          }
        } else if constexpr (MODE == 1){
          int h = col >> 6, d = col & 63;
          ((u16*)o0)[((size_t)h * KLEN + row) * DH + d] = f2b(v);
        } else {
          ((float*)o0)[(size_t)row * DM + col] = v;
        }
      }
    }
  }
}

// ---------------- fused flash attention, 64-row blocks, 4 waves ----------------
// r8 structure + snake i-block pairing (co-resident pairs have ~equal total
// j-tiles: (0,15),(1,14)...) + softmax row-sum via ones-MFMA (matrix pipe,
// replacing the DPP-add tree) + Pt writes folded into the exp loop.

__global__ __launch_bounds__(256, 2) void attn_k(
    const u16* __restrict__ qB,  const u16* __restrict__ kB,
    const u16* __restrict__ vB,  const u16* __restrict__ rhB,
    const float* __restrict__ rwb, const float* __restrict__ rrb,
    u16* __restrict__ av)
{
  __shared__ u16 Kt[2][64 * 64];      // [j][d] swizzled     16 KB
  __shared__ u16 Vt[2][64 * 64];      // [d][j] swizzled     16 KB
  __shared__ u16 Rb[2][64 * 64];      // band [t'][d] swz    16 KB
  __shared__ u16 Pt[4][16 * 64];      // per-wave P [r][j]    8 KB
  __shared__ u16 Pbd[2][64 * 64];     // BD [r][t'] row-XOR  16 KB   total 72 KB

  const int tid = threadIdx.x, lane = tid & 63, w = tid >> 6;
  const int lr = lane >> 4, lc = lane & 15;

  // XCD remap (bid%8 = XCD, i fastest) + snake pairing for tail balance
  const int bid = blockIdx.x;
  const int nid = (bid & 7) * 128 + (bid >> 3);
  const int tt = nid & 15;
  const int iblk = (tt & 1) ? (15 - (tt >> 1)) : (tt >> 1);
  const int i0 = iblk * 64;
  const int h  = (nid >> 4) & 15;
  const int b  = nid >> 8;
  const size_t bh = (size_t)b * NH + h;

  const float SCL = 0.18033688011112042f;   // 0.125 * log2(e) -> exp2 domain

  // Q fragments with biases, pre-scaled (rows i0 + w*16 + lc)
  bf16x8 qw_[2], qr_[2];
  #pragma unroll
  for (int ks = 0; ks < 2; ks++){
    bf16x8 qv = *(const bf16x8*)(qB + (bh * QLEN + i0 + w * 16 + lc) * DH + ks * 32 + lr * 8);
    #pragma unroll
    for (int e2 = 0; e2 < 8; e2++){
      int d = ks * 32 + lr * 8 + e2;
      float q32 = b2f((u16)qv[e2]);
      qw_[ks][e2] = (short)f2bn((q32 + rwb[h * DH + d]) * SCL);
      qr_[ks][e2] = (short)f2bn((q32 + rrb[h * DH + d]) * SCL);
    }
  }

  // ones vector (bf16 1.0) for row-sum MFMA
  bf16x8 onesv;
  #pragma unroll
  for (int e2 = 0; e2 < 8; e2++) onesv[e2] = (short)0x3F80;

  // jt-invariant sheared-pickup metadata
  int pbo[4][4]; bool sel[4][4], mskc[4][4];
  #pragma unroll
  for (int n = 0; n < 4; n++)
    #pragma unroll
    for (int e = 0; e < 4; e++){
      int il = w * 16 + lr * 4 + e;
      int dd = n * 16 + lc - il;
      pbo[n][e] = il * 128 + ((2 * (dd & 63)) ^ ((il & 7) << 4));
      sel[n][e] = dd < 0;
      mskc[n][e] = dd > 0;
    }

  f32x4 O[4];
  float mx[4], sm[4];
  #pragma unroll
  for (int df = 0; df < 4; df++) O[df] = (f32x4){0.f, 0.f, 0.f, 0.f};
  #pragma unroll
  for (int e = 0; e < 4; e++){ mx[e] = -3.0e38f; sm[e] = 0.f; }

  const char* kgb = (const char*)(kB + bh * (size_t)KLEN * DH);
  const char* vgb = (const char*)(vB + bh * (size_t)KLEN * DH);   // [DH][KLEN]
  const char* rgb = (const char*)(rhB + (size_t)h * KLEN * DH);

  const int jtiles = (i0 >> 6) + 17;

  // ---- prologue: stage prev band -> Rb[1], tile0 K/V/band -> [0] ----
  {
    int tbp = 959 - i0;
    #pragma unroll
    for (int rnd = 0; rnd < 2; rnd++){
      int c = rnd * 256 + tid;
      int row = c >> 3;
      int ch = (c & 7) ^ ((row ^ (row >> 3)) & 7);
      int t = tbp + row; t = t < 0 ? 0 : t;
      stage16(rgb + (size_t)t * 128 + ch * 16, (char*)&Rb[1][0] + c * 16);
    }
    __builtin_amdgcn_sched_barrier(0);
    #pragma unroll
    for (int rnd = 0; rnd < 2; rnd++){
      int c = rnd * 256 + tid;
      int row = c >> 3;
      int ch = (c & 7) ^ ((row ^ (row >> 3)) & 7);
      stage16(kgb + (size_t)row * 128 + ch * 16, (char*)&Kt[0][0] + c * 16);
      stage16(vgb + (size_t)row * 4096 + ch * 16, (char*)&Vt[0][0] + c * 16);
      int t = 1023 - i0 + row;
      stage16(rgb + (size_t)t * 128 + ch * 16, (char*)&Rb[0][0] + c * 16);
    }
    __builtin_amdgcn_sched_barrier(0);
    asm volatile("s_waitcnt vmcnt(6)" ::: "memory");
    __builtin_amdgcn_s_barrier();
    // BD^T for prev band -> Pbd[1]
    #pragma unroll
    for (int n2 = 0; n2 < 4; n2++){
      bf16x8 a0 = *(const bf16x8*)((const char*)&Rb[1][0] + swz(n2 * 16 + lc, lr * 16));
      bf16x8 a1 = *(const bf16x8*)((const char*)&Rb[1][0] + swz(n2 * 16 + lc, 64 + lr * 16));
      f32x4 z = (f32x4){0.f, 0.f, 0.f, 0.f};
      z = MFMA16(a0, qr_[0], z);
      z = MFMA16(a1, qr_[1], z);
      int row = w * 16 + lc;
      uint2 pr; pr.x = pk2(z[0], z[1]); pr.y = pk2(z[2], z[3]);
      *(uint2*)((char*)&Pbd[1][0] + row * 128 + ((n2 * 32 + lr * 8) ^ ((row & 7) << 4))) = pr;
    }
  }

  for (int jt = 0; jt < jtiles; jt++){
    const int j0 = jt * 64;
    const int cur = jt & 1, nxt = cur ^ 1;

    // issue next-tile stages (6; stay in flight across the barrier)
    {
      int jn = (jt + 1 < jtiles) ? j0 + 64 : j0;
      int tb = 1023 - i0 + jn;
      #pragma unroll
      for (int rnd = 0; rnd < 2; rnd++){
        int c = rnd * 256 + tid;
        int row = c >> 3;
        int ch = (c & 7) ^ ((row ^ (row >> 3)) & 7);
        stage16(kgb + (size_t)(jn + row) * 128 + ch * 16, (char*)&Kt[nxt][0] + c * 16);
        stage16(vgb + (size_t)row * 4096 + jn * 2 + ch * 16, (char*)&Vt[nxt][0] + c * 16);
        int t = tb + row; t = t > 2047 ? 2047 : t;
        stage16(rgb + (size_t)t * 128 + ch * 16, (char*)&Rb[nxt][0] + c * 16);
      }
    }
    __builtin_amdgcn_sched_barrier(0);
    asm volatile("s_waitcnt vmcnt(6)" ::: "memory");
    __builtin_amdgcn_s_barrier();

    // AC = scaled (q + r_w_bias) K^T
    f32x4 s[4];
    __builtin_amdgcn_s_setprio(1);
    #pragma unroll
    for (int n = 0; n < 4; n++){
      bf16x8 k0f = *(const bf16x8*)((const char*)&Kt[cur][0] + swz(n * 16 + lc, lr * 16));
      bf16x8 k1f = *(const bf16x8*)((const char*)&Kt[cur][0] + swz(n * 16 + lc, 64 + lr * 16));
      f32x4 z = (f32x4){0.f, 0.f, 0.f, 0.f};
      z = MFMA16(qw_[0], k0f, z);
      z = MFMA16(qw_[1], k1f, z);
      s[n] = z;
    }
    // BD^T for current band -> Pbd[cur] (packed b64 stores)
    #pragma unroll
    for (int n2 = 0; n2 < 4; n2++){
      bf16x8 a0 = *(const bf16x8*)((const char*)&Rb[cur][0] + swz(n2 * 16 + lc, lr * 16));
      bf16x8 a1 = *(const bf16x8*)((const char*)&Rb[cur][0] + swz(n2 * 16 + lc, 64 + lr * 16));
      f32x4 z = (f32x4){0.f, 0.f, 0.f, 0.f};
      z = MFMA16(a0, qr_[0], z);
      z = MFMA16(a1, qr_[1], z);
      int row = w * 16 + lc;
      uint2 pr; pr.x = pk2(z[0], z[1]); pr.y = pk2(z[2], z[3]);
      *(uint2*)((char*)&Pbd[cur][0] + row * 128 + ((n2 * 32 + lr * 8) ^ ((row & 7) << 4))) = pr;
    }
    __builtin_amdgcn_s_setprio(0);
    asm volatile("s_waitcnt lgkmcnt(0)" ::: "memory");
    __builtin_amdgcn_sched_barrier(0);

    // sheared BD pickup + online softmax (exp2 domain, defer-max THR=8)
    const char* pbC = (const char*)&Pbd[cur][0];
    const char* pbP = (const char*)&Pbd[nxt][0];
    const bool maskT = (jt == jtiles - 1);
    float tmv[4];
    #pragma unroll
    for (int e = 0; e < 4; e++){
      float tm = -3.0e38f;
      #pragma unroll
      for (int n = 0; n < 4; n++){
        u16 bd = *(const u16*)((sel[n][e] ? pbP : pbC) + pbo[n][e]);
        float x = s[n][e] + b2f(bd);
        if (maskT && mskc[n][e]) x = -1.0e30f;    // j > i + MLEN
        s[n][e] = x;
        tm = fmaxf(tm, x);
      }
      tm = dppmax<0x121>(tm); tm = dppmax<0x122>(tm);
      tm = dppmax<0x124>(tm); tm = dppmax<0x128>(tm);
      tmv[e] = tm;
    }
    bool need = false;
    float nm[4];
    #pragma unroll
    for (int e = 0; e < 4; e++){
      nm[e] = fmaxf(mx[e], tmv[e]);
      need = need | (tmv[e] > mx[e] + 8.0f);
    }
    if (__any(need)){
      #pragma unroll
      for (int e = 0; e < 4; e++){
        float fc = __builtin_amdgcn_exp2f(mx[e] - nm[e]);
        mx[e] = nm[e];
        sm[e] *= fc;
        #pragma unroll
        for (int df = 0; df < 4; df++) O[df][e] *= fc;
      }
    }
    // exp + P -> LDS (cvt/ds_write hide under exp latency)
    #pragma unroll
    for (int e = 0; e < 4; e++)
      #pragma unroll
      for (int n = 0; n < 4; n++){
        float pv = __builtin_amdgcn_exp2f(s[n][e] - mx[e]);   // <= 2^8
        *(u16*)((char*)&Pt[w][0] + swz(lr * 4 + e, (n * 16 + lc) * 2)) = f2bn(pv);
      }
    asm volatile("s_waitcnt lgkmcnt(0)" ::: "memory");
    __builtin_amdgcn_sched_barrier(0);

    // O += P @ V; row-sums via ones-MFMA on the idle matrix pipe
    bf16x8 pa0 = *(const bf16x8*)((const char*)&Pt[w][0] + swz(lc, lr * 16));
    bf16x8 pa1 = *(const bf16x8*)((const char*)&Pt[w][0] + swz(lc, 64 + lr * 16));
    __builtin_amdgcn_s_setprio(1);
    f32x4 zs = (f32x4){0.f, 0.f, 0.f, 0.f};
    zs = MFMA16(pa0, onesv, zs);
    zs = MFMA16(pa1, onesv, zs);
    #pragma unroll
    for (int df = 0; df < 4; df++){
      bf16x8 v0 = *(const bf16x8*)((const char*)&Vt[cur][0] + swz(df * 16 + lc, lr * 16));
      bf16x8 v1 = *(const bf16x8*)((const char*)&Vt[cur][0] + swz(df * 16 + lc, 64 + lr * 16));
      O[df] = MFMA16(pa0, v0, O[df]);
      O[df] = MFMA16(pa1, v1, O[df]);
    }
    __builtin_amdgcn_s_setprio(0);
    #pragma unroll
    for (int e = 0; e < 4; e++) sm[e] += zs[e];
    // all reads of [cur] done before next iteration stages into it
    __builtin_amdgcn_s_barrier();
  }

  asm volatile("s_waitcnt vmcnt(0)" ::: "memory");

  #pragma unroll
  for (int e = 0; e < 4; e++){
    float is = 1.0f / sm[e];
    #pragma unroll
    for (int df = 0; df < 4; df++){
      int i = i0 + w * 16 + lr * 4 + e;
      av[(size_t)(i * BSZ + b) * DM + h * DH + df * 16 + lc] = f2bn(O[df][e] * is);
    }
  }
}

// ---------------- residual + LayerNorm ----------------

__global__ __launch_bounds__(256) void ln_k(const float* __restrict__ w,
                                            const float* __restrict__ ao,
                                            const float* __restrict__ gam,
                                            const float* __restrict__ bet,
                                            float* __restrict__ out){
  __shared__ float red[8];
  const int rw = blockIdx.x, t = threadIdx.x, lane = t & 63, wv = t >> 6;
  const float* wr_ = w + (size_t)rw * DM;
  const float* ar_ = ao + (size_t)rw * DM;
  float x[4];
  float s = 0.f, ss = 0.f;
  #pragma unroll
  for (int k2 = 0; k2 < 4; k2++){
    int c = t + k2 * 256;
    float xv = wr_[c] + ar_[c];
    x[k2] = xv; s += xv; ss += xv * xv;
  }
  #pragma unroll
  for (int m2 = 1; m2 < 64; m2 <<= 1){ s += __shfl_xor(s, m2); ss += __shfl_xor(ss, m2); }
  if (lane == 0){ red[wv] = s; red[4 + wv] = ss; }
  __syncthreads();
  s  = red[0] + red[1] + red[2] + red[3];
  ss = red[4] + red[5] + red[6] + red[7];
  float mu = s * (1.f / DM);
  float var = ss * (1.f / DM) - mu * mu;
  float rs = rsqrtf(var + 1e-5f);
  #pragma unroll
  for (int k2 = 0; k2 < 4; k2++){
    int c = t + k2 * 256;
    out[(size_t)rw * DM + c] = (x[k2] - mu) * rs * gam[c] + bet[c];
  }
}

// ---------------- launch ----------------

extern "C" void kernel_launch(void* const* d_in, const int* in_sizes, int n_in,
                              void* d_out, int out_size, void* d_ws, size_t ws_size,
                              hipStream_t stream)
{
  (void)in_sizes; (void)n_in; (void)out_size; (void)ws_size;
  const float* w    = (const float*)d_in[0];
  const float* r    = (const float*)d_in[1];
  const float* mems = (const float*)d_in[2];
  const float* Wqkv = (const float*)d_in[3];
  const float* Wr   = (const float*)d_in[4];
  const float* Wo   = (const float*)d_in[5];
  const float* rwb  = (const float*)d_in[6];
  const float* rrb  = (const float*)d_in[7];
  const float* gam  = (const float*)d_in[8];
  const float* bet  = (const float*)d_in[9];
  float* out = (float*)d_out;

  char* ws = (char*)d_ws;
  size_t off = 0;
  auto alloc = [&](size_t n){ char* p = ws + off; off += (n + 255) & ~(size_t)255; return p; };
  u16* catB  = (u16*)alloc((size_t)KLEN * BSZ * DM * 2);
  u16* rB    = (u16*)alloc((size_t)KLEN * DM * 2);
  u16* WqkvT = (u16*)alloc((size_t)3 * DM * DM * 2);
  u16* WrT   = (u16*)alloc((size_t)DM * DM * 2);
  u16* WoT   = (u16*)alloc((size_t)DM * DM * 2);
  u16* qBuf  = (u16*)alloc((size_t)BSZ * NH * QLEN * DH * 2);
  u16* kBp   = (u16*)alloc((size_t)BSZ * NH * KLEN * DH * 2);
  u16* vBp   = (u16*)alloc((size_t)BSZ * NH * KLEN * DH * 2);   // d-major
  u16* rhB   = (u16*)alloc((size_t)NH * KLEN * DH * 2);
  u16* av    = (u16*)alloc((size_t)QLEN * BSZ * DM * 2);
  float* ao  = (float*)alloc((size_t)QLEN * BSZ * DM * 4);

  conv_all<<<dim3(8192 + 2048), 256, 0, stream>>>(mems, w, r, catB, rB);
  transpose3<<<dim3(160, 32), 256, 0, stream>>>(Wqkv, WqkvT, Wr, WrT, Wo, WoT);

  // QKV projection: [8192,1024] x [1024,3072]
  gemm_k<0><<<dim3(24, 64), 256, 0, stream>>>(catB, WqkvT, DM, qBuf, kBp, vBp);
  // R projection: [2048,1024] x [1024,1024]
  gemm_k<1><<<dim3(8, 16), 256, 0, stream>>>(rB, WrT, DM, rhB, nullptr, nullptr);

  // fused attention: 1024 blocks x 256 threads (2 blocks/CU, 72 KB LDS each)
  attn_k<<<dim3(1024), 256, 0, stream>>>(qBuf, kBp, vBp, rhB, rwb, rrb, av);

  // output projection: [4096,1024] x [1024,1024]
  gemm_k<3><<<dim3(8, 32), 256, 0, stream>>>(av, WoT, DM, ao, nullptr, nullptr);
  ln_k<<<dim3(4096), 256, 0, stream>>>(w, ao, gam, bet, out);
}